// Round 2
// baseline (1296.271 us; speedup 1.0000x reference)
//
#include <hip/hip_runtime.h>
#include <math.h>

#define SELF_VAL (-5e4f)

// ---------------- K0: transpose rotations -> rotT[(h*256+i)][k] ----------------
__global__ __launch_bounds__(256) void k_rotT(const float* __restrict__ rot,
                                              float* __restrict__ rotT)
{
    int idx = blockIdx.x * 256 + threadIdx.x;    // 0..65535
    int col = idx >> 6, k = idx & 63;
    int h = col >> 8, i = col & 255;
    rotT[idx] = rot[k * 1024 + h * 256 + i];
}

// ---------------- K1: fused qk/v GEMM (f32, 128x128 tile, 8x8/thread) ----------------
// A = queries (16384 x 512), B = [Wqk | Wv] (512 x 1024)
// writes qk, v head-major: [(b*8+h)][t][dd]
__global__ __launch_bounds__(256) void k_gemm_qkv(
    const float* __restrict__ Q, const float* __restrict__ Wqk,
    const float* __restrict__ Wv, float* __restrict__ qk, float* __restrict__ vv)
{
    __shared__ float As[16][132];   // transposed: As[k][m]
    __shared__ float Bs[16][132];
    const int bx = blockIdx.x;
    const int mt = bx >> 3, nt = bx & 7;
    const int m0 = mt * 128, n0 = nt * 128;
    const int tid = threadIdx.x;
    const int ty = tid >> 4, tx = tid & 15;
    const float* Bsrc = (n0 < 512) ? (Wqk + n0) : (Wv + (n0 - 512));
    float acc[8][8] = {};
    for (int k0 = 0; k0 < 512; k0 += 16) {
        #pragma unroll
        for (int c = 0; c < 2; c++) {
            int e = c * 256 + tid;
            int r = e >> 2, cq = e & 3;
            float4 a4 = *(const float4*)(Q + (size_t)(m0 + r) * 512 + k0 + cq * 4);
            As[cq*4+0][r] = a4.x; As[cq*4+1][r] = a4.y;
            As[cq*4+2][r] = a4.z; As[cq*4+3][r] = a4.w;
            int kk = e >> 5, nq = e & 31;
            float4 b4 = *(const float4*)(Bsrc + (size_t)(k0 + kk) * 512 + nq * 4);
            *(float4*)&Bs[kk][nq*4] = b4;
        }
        __syncthreads();
        #pragma unroll
        for (int kk = 0; kk < 16; kk++) {
            float a_[8], b_[8];
            *(float4*)&a_[0] = *(float4*)&As[kk][ty*4];
            *(float4*)&a_[4] = *(float4*)&As[kk][64 + ty*4];
            *(float4*)&b_[0] = *(float4*)&Bs[kk][tx*4];
            *(float4*)&b_[4] = *(float4*)&Bs[kk][64 + tx*4];
            #pragma unroll
            for (int i = 0; i < 8; i++)
                #pragma unroll
                for (int j = 0; j < 8; j++)
                    acc[i][j] += a_[i] * b_[j];
        }
        __syncthreads();
    }
    #pragma unroll
    for (int ig = 0; ig < 2; ig++) {
        #pragma unroll
        for (int i = 0; i < 4; i++) {
            int row = m0 + ig*64 + ty*4 + i;
            int b = row >> 11, t = row & 2047;
            #pragma unroll
            for (int jg = 0; jg < 2; jg++) {
                int n = n0 + jg*64 + tx*4;
                float4 r4 = make_float4(acc[ig*4+i][jg*4+0], acc[ig*4+i][jg*4+1],
                                        acc[ig*4+i][jg*4+2], acc[ig*4+i][jg*4+3]);
                if (n < 512) {
                    *(float4*)(qk + ((size_t)((b*8 + (n>>6))*2048 + t))*64 + (n&63)) = r4;
                } else {
                    int nv = n - 512;
                    *(float4*)(vv + ((size_t)((b*8 + (nv>>6))*2048 + t))*64 + (nv&63)) = r4;
                }
            }
        }
    }
}

// ---------------- K1b: reciprocal row norms of qk ----------------
__global__ __launch_bounds__(256) void k_rnorm(const float* __restrict__ qk,
                                               float* __restrict__ rnorm)
{
    int w = threadIdx.x >> 6, lane = threadIdx.x & 63;
    int row = blockIdx.x * 4 + w;            // 0..131071  (bm*2048+t)
    float x = qk[(size_t)row * 64 + lane];
    float s = x * x;
    #pragma unroll
    for (int d = 1; d < 64; d <<= 1) s += __shfl_xor(s, d);
    if (lane == 0) rnorm[row] = 1.0f / fmaxf(sqrtf(s), 1e-12f);
}

// ---------------- K2: hash projection + signed argmax (register/SGPR stream) ----------------
__global__ __launch_bounds__(256) void k_hash(const float* __restrict__ qk,
    const float* __restrict__ rotT, unsigned* __restrict__ buckets)
{
    const int bm = blockIdx.x >> 3;
    const int tok = ((blockIdx.x & 7) << 8) + threadIdx.x;
    const float* qrow = qk + ((size_t)(bm*2048 + tok))*64;
    float q[64];
    #pragma unroll
    for (int kq = 0; kq < 16; kq++) {
        float4 v4 = *(const float4*)(qrow + kq*4);
        q[kq*4+0] = v4.x; q[kq*4+1] = v4.y; q[kq*4+2] = v4.z; q[kq*4+3] = v4.w;
    }
    #pragma unroll
    for (int h = 0; h < 4; h++) {
        const float* base = rotT + (size_t)h * 256 * 64;
        float bv = -3.402823466e38f; unsigned bi = 0;
        for (int i = 0; i < 256; i++) {
            const float* col = base + i * 64;
            float acc = 0.f;
            #pragma unroll
            for (int k = 0; k < 64; k++) acc = fmaf(q[k], col[k], acc);
            if (acc > bv) { bv = acc; bi = (unsigned)i; }
            float nacc = -acc;
            if (nacc > bv) { bv = nacc; bi = (unsigned)(256 + i); }
        }
        buckets[((size_t)(bm*4 + h))*2048 + tok] = bi;
    }
}

// ---------------- K3: stable counting sort per (bm,hash) ----------------
__global__ __launch_bounds__(256) void k_sort(const unsigned* __restrict__ buckets,
                                              unsigned* __restrict__ st)
{
    __shared__ unsigned whist[4][512];
    __shared__ unsigned baseb[512];
    const int seg = blockIdx.x;                  // bm*4+h
    const unsigned* bk = buckets + (size_t)seg * 2048;
    unsigned* out = st + (size_t)seg * 2048;
    const int tid = threadIdx.x, w = tid >> 6, lane = tid & 63;
    for (int b = tid; b < 2048; b += 256) ((unsigned*)whist)[b] = 0u;
    __syncthreads();
    unsigned myb[8];
    #pragma unroll
    for (int r = 0; r < 8; r++) {
        int pos = w*512 + r*64 + lane;
        myb[r] = bk[pos];
        atomicAdd(&whist[w][myb[r]], 1u);
    }
    __syncthreads();
    for (int b = tid; b < 512; b += 256) {
        unsigned p = 0;
        #pragma unroll
        for (int ww = 0; ww < 4; ww++) { unsigned t = whist[ww][b]; whist[ww][b] = p; p += t; }
        baseb[b] = p;
    }
    __syncthreads();
    if (tid == 0) {
        unsigned run = 0;
        for (int b = 0; b < 512; b++) { unsigned t = baseb[b]; baseb[b] = run; run += t; }
    }
    __syncthreads();
    for (int b = tid; b < 512; b += 256) {
        unsigned bb = baseb[b];
        #pragma unroll
        for (int ww = 0; ww < 4; ww++) whist[ww][b] += bb;
    }
    __syncthreads();
    for (int r = 0; r < 8; r++) {
        unsigned b = myb[r];
        int pos = w*512 + r*64 + lane;
        unsigned base = whist[w][b];             // read before this round's bumps
        unsigned rank = 0;
        for (int j = 0; j < 64; j++) {
            unsigned bj = __shfl(b, j);
            rank += (j < lane && bj == b) ? 1u : 0u;
        }
        out[base + rank] = (unsigned)pos;
        atomicAdd(&whist[w][b], 1u);
    }
}

// ---------------- K4: chunked LSH attention ----------------
__global__ __launch_bounds__(256) void k_attn(const float* __restrict__ qk,
    const float* __restrict__ vv, const float* __restrict__ rnorm,
    const unsigned* __restrict__ st, float* __restrict__ oh,
    float* __restrict__ logits)
{
    __shared__ float qs[68][68];
    __shared__ float vs[68][68];
    __shared__ unsigned P[68];
    __shared__ float rn[68];
    const int sid = blockIdx.x;
    const int stripi = sid & 31;
    const int seg = sid >> 5;
    const int bm = seg >> 2, h = seg & 3;
    const int G0 = (h*512 + stripi*16) * 4;      // first q slot (global, 0..8191)
    const int tid = threadIdx.x;
    for (int j = tid; j < 68; j += 256) {
        int G = (G0 - 4 + j) & 8191;
        int hg = G >> 11, sg = G & 2047;
        unsigned tok = st[((size_t)(bm*4 + hg))*2048 + sg];
        P[j] = tok;
        rn[j] = rnorm[bm*2048 + (int)tok];
    }
    __syncthreads();
    for (int e = tid; e < 68*16; e += 256) {
        int j = e >> 4, fq = e & 15;
        unsigned tok = P[j];
        size_t base = ((size_t)(bm*2048 + (int)tok))*64 + fq*4;
        *(float4*)&qs[j][fq*4] = *(const float4*)(qk + base);
        *(float4*)&vs[j][fq*4] = *(const float4*)(vv + base);
    }
    __syncthreads();
    const int w = tid >> 6, lane = tid & 63;
    const int half = lane >> 5, qi = (lane >> 3) & 3, jj = lane & 7;
    const int fb = lane & 7;
    for (int cp = 0; cp < 2; cp++) {
        int c = w*4 + cp*2 + half;               // local chunk 0..15
        int jq = 4 + c*4 + qi;
        int jk = c*4 + jj;
        float dot = 0.f;
        #pragma unroll
        for (int fq = 0; fq < 16; fq++) {
            float4 q4 = *(float4*)&qs[jq][fq*4];
            float4 k4 = *(float4*)&qs[jk][fq*4];
            dot += q4.x*k4.x + q4.y*k4.y + q4.z*k4.z + q4.w*k4.w;
        }
        dot *= 0.125f * rn[jk];
        if (P[jq] == P[jk]) dot = SELF_VAL;
        float m = dot;
        m = fmaxf(m, __shfl_xor(m, 1));
        m = fmaxf(m, __shfl_xor(m, 2));
        m = fmaxf(m, __shfl_xor(m, 4));
        float ex = expf(dot - m);
        float s = ex;
        s += __shfl_xor(s, 1); s += __shfl_xor(s, 2); s += __shfl_xor(s, 4);
        float lse = m + logf(s);
        float p = expf(dot - lse);
        unsigned tq = P[jq];
        if (jj == 0) logits[((size_t)(bm*4 + h))*2048 + tq] = lse;
        float a0=0,a1=0,a2=0,a3=0,a4a=0,a5=0,a6=0,a7=0;
        #pragma unroll
        for (int j2 = 0; j2 < 8; j2++) {
            float pj = __shfl(p, (lane & 0x38) | j2);
            float4 va = *(float4*)&vs[c*4 + j2][fb*8];
            float4 vb = *(float4*)&vs[c*4 + j2][fb*8 + 4];
            a0 += pj*va.x; a1 += pj*va.y; a2 += pj*va.z; a3 += pj*va.w;
            a4a += pj*vb.x; a5 += pj*vb.y; a6 += pj*vb.z; a7 += pj*vb.w;
        }
        float* dst = oh + ((size_t)((bm*4 + h)*2048 + (int)tq))*64 + fb*8;
        *(float4*)dst = make_float4(a0, a1, a2, a3);
        *(float4*)(dst + 4) = make_float4(a4a, a5, a6, a7);
    }
}

// ---------------- K5: combine hash rounds ----------------
__global__ __launch_bounds__(256) void k_combine(const float* __restrict__ oh,
    const float* __restrict__ logits, float* __restrict__ comb)
{
    int w = threadIdx.x >> 6, lane = threadIdx.x & 63;
    int row = blockIdx.x * 4 + w;                // bm*2048+t
    int bm = row >> 11, t = row & 2047;
    int b = bm >> 3, head = bm & 7;
    float l0 = logits[((size_t)(bm*4 + 0))*2048 + t];
    float l1 = logits[((size_t)(bm*4 + 1))*2048 + t];
    float l2 = logits[((size_t)(bm*4 + 2))*2048 + t];
    float l3 = logits[((size_t)(bm*4 + 3))*2048 + t];
    float m = fmaxf(fmaxf(l0, l1), fmaxf(l2, l3));
    float e0 = expf(l0 - m), e1 = expf(l1 - m), e2 = expf(l2 - m), e3 = expf(l3 - m);
    float inv = 1.0f / (e0 + e1 + e2 + e3);
    float o = 0.f;
    o += (e0*inv) * oh[((size_t)((bm*4+0)*2048 + t))*64 + lane];
    o += (e1*inv) * oh[((size_t)((bm*4+1)*2048 + t))*64 + lane];
    o += (e2*inv) * oh[((size_t)((bm*4+2)*2048 + t))*64 + lane];
    o += (e3*inv) * oh[((size_t)((bm*4+3)*2048 + t))*64 + lane];
    comb[((size_t)(b*2048 + t))*512 + head*64 + lane] = o;
}

// ---------------- K6: output GEMM + bias (f32, 128x128 tile, 8x8/thread) ----------------
__global__ __launch_bounds__(256) void k_gemm_out(
    const float* __restrict__ A, const float* __restrict__ Wout,
    const float* __restrict__ bias, float* __restrict__ out)
{
    __shared__ float As[16][132];
    __shared__ float Bs[16][132];
    const int bx = blockIdx.x;
    const int mt = bx >> 2, nt = bx & 3;
    const int m0 = mt * 128, n0 = nt * 128;
    const int tid = threadIdx.x;
    const int ty = tid >> 4, tx = tid & 15;
    float acc[8][8] = {};
    for (int k0 = 0; k0 < 512; k0 += 16) {
        #pragma unroll
        for (int c = 0; c < 2; c++) {
            int e = c * 256 + tid;
            int r = e >> 2, cq = e & 3;
            float4 a4 = *(const float4*)(A + (size_t)(m0 + r) * 512 + k0 + cq * 4);
            As[cq*4+0][r] = a4.x; As[cq*4+1][r] = a4.y;
            As[cq*4+2][r] = a4.z; As[cq*4+3][r] = a4.w;
            int kk = e >> 5, nq = e & 31;
            float4 b4 = *(const float4*)(Wout + (size_t)(k0 + kk) * 512 + n0 + nq * 4);
            *(float4*)&Bs[kk][nq*4] = b4;
        }
        __syncthreads();
        #pragma unroll
        for (int kk = 0; kk < 16; kk++) {
            float a_[8], b_[8];
            *(float4*)&a_[0] = *(float4*)&As[kk][ty*4];
            *(float4*)&a_[4] = *(float4*)&As[kk][64 + ty*4];
            *(float4*)&b_[0] = *(float4*)&Bs[kk][tx*4];
            *(float4*)&b_[4] = *(float4*)&Bs[kk][64 + tx*4];
            #pragma unroll
            for (int i = 0; i < 8; i++)
                #pragma unroll
                for (int j = 0; j < 8; j++)
                    acc[i][j] += a_[i] * b_[j];
        }
        __syncthreads();
    }
    #pragma unroll
    for (int ig = 0; ig < 2; ig++) {
        #pragma unroll
        for (int i = 0; i < 4; i++) {
            int row = m0 + ig*64 + ty*4 + i;
            #pragma unroll
            for (int jg = 0; jg < 2; jg++) {
                int n = n0 + jg*64 + tx*4;
                float4 bb = *(const float4*)(bias + n);
                float4 r4 = make_float4(acc[ig*4+i][jg*4+0] + bb.x, acc[ig*4+i][jg*4+1] + bb.y,
                                        acc[ig*4+i][jg*4+2] + bb.z, acc[ig*4+i][jg*4+3] + bb.w);
                *(float4*)(out + (size_t)row * 512 + n) = r4;
            }
        }
    }
}

extern "C" void kernel_launch(void* const* d_in, const int* in_sizes, int n_in,
                              void* d_out, int out_size, void* d_ws, size_t ws_size,
                              hipStream_t stream)
{
    const float* Q    = (const float*)d_in[0];
    const float* Wqk  = (const float*)d_in[3];
    const float* Wv   = (const float*)d_in[4];
    const float* Wout = (const float*)d_in[5];
    const float* bout = (const float*)d_in[6];
    const float* rot  = (const float*)d_in[7];
    float* ws = (float*)d_ws;
    float* qk     = ws;                       // 8,388,608
    float* vv     = ws + 8388608;             // 8,388,608
    float* oh     = ws + 16777216;            // 33,554,432
    float* comb   = ws + 50331648;            // 8,388,608
    float* rnorm  = ws + 58720256;            // 131,072
    float* logits = ws + 58851328;            // 524,288
    unsigned* buckets = (unsigned*)(ws + 59375616);   // 524,288
    unsigned* st      = (unsigned*)(ws + 59899904);   // 524,288
    float* rotT   = ws + 60424192;            // 65,536
    float* out = (float*)d_out;

    k_rotT    <<<dim3(256),  dim3(256), 0, stream>>>(rot, rotT);
    k_gemm_qkv<<<dim3(1024), dim3(256), 0, stream>>>(Q, Wqk, Wv, qk, vv);
    k_rnorm   <<<dim3(32768),dim3(256), 0, stream>>>(qk, rnorm);
    k_hash    <<<dim3(512),  dim3(256), 0, stream>>>(qk, rotT, buckets);
    k_sort    <<<dim3(256),  dim3(256), 0, stream>>>(buckets, st);
    k_attn    <<<dim3(8192), dim3(256), 0, stream>>>(qk, vv, rnorm, st, oh, logits);
    k_combine <<<dim3(32768),dim3(256), 0, stream>>>(oh, logits, comb);
    k_gemm_out<<<dim3(512),  dim3(256), 0, stream>>>(comb, Wout, bout, out);
}

// Round 3
// 958.521 us; speedup vs baseline: 1.3524x; 1.3524x over previous
//
#include <hip/hip_runtime.h>
#include <math.h>

#define SELF_VAL (-5e4f)

// ---------------- K0: re-layout rotations -> rotT2[h][k][col]  (4 x 64 x 256) ----------------
__global__ __launch_bounds__(256) void k_rotT(const float* __restrict__ rot,
                                              float* __restrict__ rotT2)
{
    int idx = blockIdx.x * 256 + threadIdx.x;    // 0..65535
    int h = idx >> 14, k = (idx >> 8) & 63, col = idx & 255;
    rotT2[idx] = rot[k * 1024 + h * 256 + col];
}

// ---------------- K1: fused qk/v GEMM (f32, 128x128 tile, 8x8/thread) ----------------
// A = queries (16384 x 512), B = [Wqk | Wv] (512 x 1024)
// writes qk, v head-major: [(b*8+h)][t][dd]
__global__ __launch_bounds__(256) void k_gemm_qkv(
    const float* __restrict__ Q, const float* __restrict__ Wqk,
    const float* __restrict__ Wv, float* __restrict__ qk, float* __restrict__ vv)
{
    __shared__ float As[16][132];   // transposed: As[k][m]
    __shared__ float Bs[16][132];
    const int bx = blockIdx.x;
    const int mt = bx >> 3, nt = bx & 7;
    const int m0 = mt * 128, n0 = nt * 128;
    const int tid = threadIdx.x;
    const int ty = tid >> 4, tx = tid & 15;
    const float* Bsrc = (n0 < 512) ? (Wqk + n0) : (Wv + (n0 - 512));
    float acc[8][8] = {};
    for (int k0 = 0; k0 < 512; k0 += 16) {
        #pragma unroll
        for (int c = 0; c < 2; c++) {
            int e = c * 256 + tid;
            int r = e >> 2, cq = e & 3;
            float4 a4 = *(const float4*)(Q + (size_t)(m0 + r) * 512 + k0 + cq * 4);
            As[cq*4+0][r] = a4.x; As[cq*4+1][r] = a4.y;
            As[cq*4+2][r] = a4.z; As[cq*4+3][r] = a4.w;
            int kk = e >> 5, nq = e & 31;
            float4 b4 = *(const float4*)(Bsrc + (size_t)(k0 + kk) * 512 + nq * 4);
            *(float4*)&Bs[kk][nq*4] = b4;
        }
        __syncthreads();
        #pragma unroll
        for (int kk = 0; kk < 16; kk++) {
            float a_[8], b_[8];
            *(float4*)&a_[0] = *(float4*)&As[kk][ty*4];
            *(float4*)&a_[4] = *(float4*)&As[kk][64 + ty*4];
            *(float4*)&b_[0] = *(float4*)&Bs[kk][tx*4];
            *(float4*)&b_[4] = *(float4*)&Bs[kk][64 + tx*4];
            #pragma unroll
            for (int i = 0; i < 8; i++)
                #pragma unroll
                for (int j = 0; j < 8; j++)
                    acc[i][j] += a_[i] * b_[j];
        }
        __syncthreads();
    }
    #pragma unroll
    for (int ig = 0; ig < 2; ig++) {
        #pragma unroll
        for (int i = 0; i < 4; i++) {
            int row = m0 + ig*64 + ty*4 + i;
            int b = row >> 11, t = row & 2047;
            #pragma unroll
            for (int jg = 0; jg < 2; jg++) {
                int n = n0 + jg*64 + tx*4;
                float4 r4 = make_float4(acc[ig*4+i][jg*4+0], acc[ig*4+i][jg*4+1],
                                        acc[ig*4+i][jg*4+2], acc[ig*4+i][jg*4+3]);
                if (n < 512) {
                    *(float4*)(qk + ((size_t)((b*8 + (n>>6))*2048 + t))*64 + (n&63)) = r4;
                } else {
                    int nv = n - 512;
                    *(float4*)(vv + ((size_t)((b*8 + (nv>>6))*2048 + t))*64 + (nv&63)) = r4;
                }
            }
        }
    }
}

// ---------------- K1b: reciprocal row norms of qk ----------------
__global__ __launch_bounds__(256) void k_rnorm(const float* __restrict__ qk,
                                               float* __restrict__ rnorm)
{
    int w = threadIdx.x >> 6, lane = threadIdx.x & 63;
    int row = blockIdx.x * 4 + w;            // 0..131071  (bm*2048+t)
    float x = qk[(size_t)row * 64 + lane];
    float s = x * x;
    #pragma unroll
    for (int d = 1; d < 64; d <<= 1) s += __shfl_xor(s, d);
    if (lane == 0) rnorm[row] = 1.0f / fmaxf(sqrtf(s), 1e-12f);
}

// ---------------- K2: hash = f32 GEMM (64 tokens x 256 cols, K=64) + signed argmax ----------------
__global__ __launch_bounds__(256) void k_hash(const float* __restrict__ qk,
    const float* __restrict__ rotT2, unsigned* __restrict__ buckets)
{
    __shared__ float As[64][68];    // As[k][row]  (transposed A tile)
    __shared__ float Bs[64][260];   // Bs[k][col]; also reused as argmax scratch
    const int row0 = blockIdx.x * 64;            // global token row (bm*2048+t)
    const int tid = threadIdx.x;
    const int ty = tid >> 5, tx = tid & 31;      // ty 0..7, tx 0..31
    // --- stage A transposed: thread loads 64B contiguous of one row ---
    {
        int row = tid >> 2, kq0 = (tid & 3) * 4;
        #pragma unroll
        for (int c = 0; c < 4; c++) {
            float4 a4 = *(const float4*)(qk + ((size_t)(row0 + row))*64 + (kq0 + c)*4);
            int kk = (kq0 + c) * 4;
            As[kk+0][row] = a4.x; As[kk+1][row] = a4.y;
            As[kk+2][row] = a4.z; As[kk+3][row] = a4.w;
        }
    }
    for (int h = 0; h < 4; h++) {
        __syncthreads();   // As ready (h=0) / previous reduce readers done
        // --- stage Bs[k][col] from rotT2[h][k][col] (coalesced) ---
        {
            const float* src = rotT2 + (size_t)h * 64 * 256;
            #pragma unroll
            for (int c = 0; c < 16; c++) {
                int e = c * 256 + tid;
                int k = e >> 6, colq = e & 63;
                float4 b4 = *(const float4*)(src + k*256 + colq*4);
                *(float4*)&Bs[k][colq*4] = b4;
            }
        }
        __syncthreads();
        // --- compute 8x8 ---
        float acc[8][8] = {};
        #pragma unroll 8
        for (int kk = 0; kk < 64; kk++) {
            float a_[8], b_[8];
            *(float4*)&a_[0] = *(float4*)&As[kk][ty*4];
            *(float4*)&a_[4] = *(float4*)&As[kk][32 + ty*4];
            *(float4*)&b_[0] = *(float4*)&Bs[kk][tx*4];
            *(float4*)&b_[4] = *(float4*)&Bs[kk][128 + tx*4];
            #pragma unroll
            for (int i = 0; i < 8; i++)
                #pragma unroll
                for (int j = 0; j < 8; j++)
                    acc[i][j] += a_[i] * b_[j];
        }
        // --- per-thread signed argmax over this thread's 8 cols ---
        float bv[8]; unsigned bi[8];
        #pragma unroll
        for (int i = 0; i < 8; i++) { bv[i] = -3.402823466e38f; bi[i] = 0u; }
        #pragma unroll
        for (int j = 0; j < 8; j++) {
            unsigned c = (j < 4) ? (unsigned)(tx*4 + j) : (unsigned)(128 + tx*4 + (j-4));
            unsigned nc = 256u + c;
            #pragma unroll
            for (int i = 0; i < 8; i++) {
                float v = acc[i][j];
                if (v > bv[i] || (v == bv[i] && c < bi[i])) { bv[i] = v; bi[i] = c; }
                float nv = -v;
                if (nv > bv[i] || (nv == bv[i] && nc < bi[i])) { bv[i] = nv; bi[i] = nc; }
            }
        }
        __syncthreads();   // done reading Bs for compute -> reuse as scratch
        float* redv = &Bs[0][0];                       // 64*32 floats
        unsigned* redi = (unsigned*)(&Bs[0][0] + 2048);// 64*32 u32
        #pragma unroll
        for (int i = 0; i < 8; i++) {
            int row = (i < 4) ? (ty*4 + i) : (32 + ty*4 + (i-4));
            redv[row*32 + tx] = bv[i];
            redi[row*32 + tx] = bi[i];
        }
        __syncthreads();
        if (tid < 64) {
            int row = tid;
            float best = -3.402823466e38f; unsigned besti = 0u;
            for (int x = 0; x < 32; x++) {
                float v = redv[row*32 + x]; unsigned ii = redi[row*32 + x];
                if (v > best || (v == best && ii < besti)) { best = v; besti = ii; }
            }
            int gr = row0 + row;
            int bm = gr >> 11, t = gr & 2047;
            buckets[((size_t)(bm*4 + h))*2048 + t] = besti;
        }
    }
}

// ---------------- K3: stable counting sort per (bm,hash) ----------------
__global__ __launch_bounds__(256) void k_sort(const unsigned* __restrict__ buckets,
                                              unsigned* __restrict__ st)
{
    __shared__ unsigned whist[4][512];
    __shared__ unsigned baseb[512];
    const int seg = blockIdx.x;                  // bm*4+h
    const unsigned* bk = buckets + (size_t)seg * 2048;
    unsigned* out = st + (size_t)seg * 2048;
    const int tid = threadIdx.x, w = tid >> 6, lane = tid & 63;
    for (int b = tid; b < 2048; b += 256) ((unsigned*)whist)[b] = 0u;
    __syncthreads();
    unsigned myb[8];
    #pragma unroll
    for (int r = 0; r < 8; r++) {
        int pos = w*512 + r*64 + lane;
        myb[r] = bk[pos];
        atomicAdd(&whist[w][myb[r]], 1u);
    }
    __syncthreads();
    for (int b = tid; b < 512; b += 256) {
        unsigned p = 0;
        #pragma unroll
        for (int ww = 0; ww < 4; ww++) { unsigned t = whist[ww][b]; whist[ww][b] = p; p += t; }
        baseb[b] = p;
    }
    __syncthreads();
    if (tid == 0) {
        unsigned run = 0;
        for (int b = 0; b < 512; b++) { unsigned t = baseb[b]; baseb[b] = run; run += t; }
    }
    __syncthreads();
    for (int b = tid; b < 512; b += 256) {
        unsigned bb = baseb[b];
        #pragma unroll
        for (int ww = 0; ww < 4; ww++) whist[ww][b] += bb;
    }
    __syncthreads();
    for (int r = 0; r < 8; r++) {
        unsigned b = myb[r];
        int pos = w*512 + r*64 + lane;
        unsigned base = whist[w][b];             // read before this round's bumps
        unsigned rank = 0;
        for (int j = 0; j < 64; j++) {
            unsigned bj = __shfl(b, j);
            rank += (j < lane && bj == b) ? 1u : 0u;
        }
        out[base + rank] = (unsigned)pos;
        atomicAdd(&whist[w][b], 1u);
    }
}

// ---------------- K4: chunked LSH attention ----------------
__global__ __launch_bounds__(256) void k_attn(const float* __restrict__ qk,
    const float* __restrict__ vv, const float* __restrict__ rnorm,
    const unsigned* __restrict__ st, float* __restrict__ oh,
    float* __restrict__ logits)
{
    __shared__ float qs[68][68];
    __shared__ float vs[68][68];
    __shared__ unsigned P[68];
    __shared__ float rn[68];
    const int sid = blockIdx.x;
    const int stripi = sid & 31;
    const int seg = sid >> 5;
    const int bm = seg >> 2, h = seg & 3;
    const int G0 = (h*512 + stripi*16) * 4;      // first q slot (global, 0..8191)
    const int tid = threadIdx.x;
    for (int j = tid; j < 68; j += 256) {
        int G = (G0 - 4 + j) & 8191;
        int hg = G >> 11, sg = G & 2047;
        unsigned tok = st[((size_t)(bm*4 + hg))*2048 + sg];
        P[j] = tok;
        rn[j] = rnorm[bm*2048 + (int)tok];
    }
    __syncthreads();
    for (int e = tid; e < 68*16; e += 256) {
        int j = e >> 4, fq = e & 15;
        unsigned tok = P[j];
        size_t base = ((size_t)(bm*2048 + (int)tok))*64 + fq*4;
        *(float4*)&qs[j][fq*4] = *(const float4*)(qk + base);
        *(float4*)&vs[j][fq*4] = *(const float4*)(vv + base);
    }
    __syncthreads();
    const int w = tid >> 6, lane = tid & 63;
    const int half = lane >> 5, qi = (lane >> 3) & 3, jj = lane & 7;
    const int fb = lane & 7;
    for (int cp = 0; cp < 2; cp++) {
        int c = w*4 + cp*2 + half;               // local chunk 0..15
        int jq = 4 + c*4 + qi;
        int jk = c*4 + jj;
        float dot = 0.f;
        #pragma unroll
        for (int fq = 0; fq < 16; fq++) {
            float4 q4 = *(float4*)&qs[jq][fq*4];
            float4 k4 = *(float4*)&qs[jk][fq*4];
            dot += q4.x*k4.x + q4.y*k4.y + q4.z*k4.z + q4.w*k4.w;
        }
        dot *= 0.125f * rn[jk];
        if (P[jq] == P[jk]) dot = SELF_VAL;
        float m = dot;
        m = fmaxf(m, __shfl_xor(m, 1));
        m = fmaxf(m, __shfl_xor(m, 2));
        m = fmaxf(m, __shfl_xor(m, 4));
        float ex = expf(dot - m);
        float s = ex;
        s += __shfl_xor(s, 1); s += __shfl_xor(s, 2); s += __shfl_xor(s, 4);
        float lse = m + logf(s);
        float p = expf(dot - lse);
        unsigned tq = P[jq];
        if (jj == 0) logits[((size_t)(bm*4 + h))*2048 + tq] = lse;
        float a0=0,a1=0,a2=0,a3=0,a4a=0,a5=0,a6=0,a7=0;
        #pragma unroll
        for (int j2 = 0; j2 < 8; j2++) {
            float pj = __shfl(p, (lane & 0x38) | j2);
            float4 va = *(float4*)&vs[c*4 + j2][fb*8];
            float4 vb = *(float4*)&vs[c*4 + j2][fb*8 + 4];
            a0 += pj*va.x; a1 += pj*va.y; a2 += pj*va.z; a3 += pj*va.w;
            a4a += pj*vb.x; a5 += pj*vb.y; a6 += pj*vb.z; a7 += pj*vb.w;
        }
        float* dst = oh + ((size_t)((bm*4 + h)*2048 + (int)tq))*64 + fb*8;
        *(float4*)dst = make_float4(a0, a1, a2, a3);
        *(float4*)(dst + 4) = make_float4(a4a, a5, a6, a7);
    }
}

// ---------------- K5: combine hash rounds ----------------
__global__ __launch_bounds__(256) void k_combine(const float* __restrict__ oh,
    const float* __restrict__ logits, float* __restrict__ comb)
{
    int w = threadIdx.x >> 6, lane = threadIdx.x & 63;
    int row = blockIdx.x * 4 + w;                // bm*2048+t
    int bm = row >> 11, t = row & 2047;
    int b = bm >> 3, head = bm & 7;
    float l0 = logits[((size_t)(bm*4 + 0))*2048 + t];
    float l1 = logits[((size_t)(bm*4 + 1))*2048 + t];
    float l2 = logits[((size_t)(bm*4 + 2))*2048 + t];
    float l3 = logits[((size_t)(bm*4 + 3))*2048 + t];
    float m = fmaxf(fmaxf(l0, l1), fmaxf(l2, l3));
    float e0 = expf(l0 - m), e1 = expf(l1 - m), e2 = expf(l2 - m), e3 = expf(l3 - m);
    float inv = 1.0f / (e0 + e1 + e2 + e3);
    float o = 0.f;
    o += (e0*inv) * oh[((size_t)((bm*4+0)*2048 + t))*64 + lane];
    o += (e1*inv) * oh[((size_t)((bm*4+1)*2048 + t))*64 + lane];
    o += (e2*inv) * oh[((size_t)((bm*4+2)*2048 + t))*64 + lane];
    o += (e3*inv) * oh[((size_t)((bm*4+3)*2048 + t))*64 + lane];
    comb[((size_t)(b*2048 + t))*512 + head*64 + lane] = o;
}

// ---------------- K6: output GEMM + bias (f32, 128x128 tile, 8x8/thread) ----------------
__global__ __launch_bounds__(256) void k_gemm_out(
    const float* __restrict__ A, const float* __restrict__ Wout,
    const float* __restrict__ bias, float* __restrict__ out)
{
    __shared__ float As[16][132];
    __shared__ float Bs[16][132];
    const int bx = blockIdx.x;
    const int mt = bx >> 2, nt = bx & 3;
    const int m0 = mt * 128, n0 = nt * 128;
    const int tid = threadIdx.x;
    const int ty = tid >> 4, tx = tid & 15;
    float acc[8][8] = {};
    for (int k0 = 0; k0 < 512; k0 += 16) {
        #pragma unroll
        for (int c = 0; c < 2; c++) {
            int e = c * 256 + tid;
            int r = e >> 2, cq = e & 3;
            float4 a4 = *(const float4*)(A + (size_t)(m0 + r) * 512 + k0 + cq * 4);
            As[cq*4+0][r] = a4.x; As[cq*4+1][r] = a4.y;
            As[cq*4+2][r] = a4.z; As[cq*4+3][r] = a4.w;
            int kk = e >> 5, nq = e & 31;
            float4 b4 = *(const float4*)(Wout + (size_t)(k0 + kk) * 512 + n0 + nq * 4);
            *(float4*)&Bs[kk][nq*4] = b4;
        }
        __syncthreads();
        #pragma unroll
        for (int kk = 0; kk < 16; kk++) {
            float a_[8], b_[8];
            *(float4*)&a_[0] = *(float4*)&As[kk][ty*4];
            *(float4*)&a_[4] = *(float4*)&As[kk][64 + ty*4];
            *(float4*)&b_[0] = *(float4*)&Bs[kk][tx*4];
            *(float4*)&b_[4] = *(float4*)&Bs[kk][64 + tx*4];
            #pragma unroll
            for (int i = 0; i < 8; i++)
                #pragma unroll
                for (int j = 0; j < 8; j++)
                    acc[i][j] += a_[i] * b_[j];
        }
        __syncthreads();
    }
    #pragma unroll
    for (int ig = 0; ig < 2; ig++) {
        #pragma unroll
        for (int i = 0; i < 4; i++) {
            int row = m0 + ig*64 + ty*4 + i;
            #pragma unroll
            for (int jg = 0; jg < 2; jg++) {
                int n = n0 + jg*64 + tx*4;
                float4 bb = *(const float4*)(bias + n);
                float4 r4 = make_float4(acc[ig*4+i][jg*4+0] + bb.x, acc[ig*4+i][jg*4+1] + bb.y,
                                        acc[ig*4+i][jg*4+2] + bb.z, acc[ig*4+i][jg*4+3] + bb.w);
                *(float4*)(out + (size_t)row * 512 + n) = r4;
            }
        }
    }
}

extern "C" void kernel_launch(void* const* d_in, const int* in_sizes, int n_in,
                              void* d_out, int out_size, void* d_ws, size_t ws_size,
                              hipStream_t stream)
{
    const float* Q    = (const float*)d_in[0];
    const float* Wqk  = (const float*)d_in[3];
    const float* Wv   = (const float*)d_in[4];
    const float* Wout = (const float*)d_in[5];
    const float* bout = (const float*)d_in[6];
    const float* rot  = (const float*)d_in[7];
    float* ws = (float*)d_ws;
    float* qk     = ws;                       // 8,388,608
    float* vv     = ws + 8388608;             // 8,388,608
    float* oh     = ws + 16777216;            // 33,554,432
    float* comb   = ws + 50331648;            // 8,388,608
    float* rnorm  = ws + 58720256;            // 131,072
    float* logits = ws + 58851328;            // 524,288
    unsigned* buckets = (unsigned*)(ws + 59375616);   // 524,288
    unsigned* st      = (unsigned*)(ws + 59899904);   // 524,288
    float* rotT2  = ws + 60424192;            // 65,536
    float* out = (float*)d_out;

    k_rotT    <<<dim3(256),  dim3(256), 0, stream>>>(rot, rotT2);
    k_gemm_qkv<<<dim3(1024), dim3(256), 0, stream>>>(Q, Wqk, Wv, qk, vv);
    k_rnorm   <<<dim3(32768),dim3(256), 0, stream>>>(qk, rnorm);
    k_hash    <<<dim3(2048), dim3(256), 0, stream>>>(qk, rotT2, buckets);
    k_sort    <<<dim3(256),  dim3(256), 0, stream>>>(buckets, st);
    k_attn    <<<dim3(8192), dim3(256), 0, stream>>>(qk, vv, rnorm, st, oh, logits);
    k_combine <<<dim3(32768),dim3(256), 0, stream>>>(oh, logits, comb);
    k_gemm_out<<<dim3(512),  dim3(256), 0, stream>>>(comb, Wout, bout, out);
}

// Round 4
// 860.352 us; speedup vs baseline: 1.5067x; 1.1141x over previous
//
#include <hip/hip_runtime.h>
#include <math.h>

#define SELF_VAL (-5e4f)

// ---------------- K0: re-layout rotations -> rotT2[h][k][col]  (4 x 64 x 256) ----------------
__global__ __launch_bounds__(256) void k_rotT(const float* __restrict__ rot,
                                              float* __restrict__ rotT2)
{
    int idx = blockIdx.x * 256 + threadIdx.x;    // 0..65535
    int h = idx >> 14, k = (idx >> 8) & 63, col = idx & 255;
    rotT2[idx] = rot[k * 1024 + h * 256 + col];
}

// ---------------- K1: fused qk/v GEMM (f32, 128x128 tile, 8x8/thread) ----------------
// A = queries (16384 x 512), B = [Wqk | Wv] (512 x 1024)
// writes qk, v head-major: [(b*8+h)][t][dd]
__global__ __launch_bounds__(256) void k_gemm_qkv(
    const float* __restrict__ Q, const float* __restrict__ Wqk,
    const float* __restrict__ Wv, float* __restrict__ qk, float* __restrict__ vv)
{
    __shared__ float As[16][132];   // transposed: As[k][m]
    __shared__ float Bs[16][132];
    const int bx = blockIdx.x;
    const int mt = bx >> 3, nt = bx & 7;
    const int m0 = mt * 128, n0 = nt * 128;
    const int tid = threadIdx.x;
    const int ty = tid >> 4, tx = tid & 15;
    const float* Bsrc = (n0 < 512) ? (Wqk + n0) : (Wv + (n0 - 512));
    float acc[8][8] = {};
    for (int k0 = 0; k0 < 512; k0 += 16) {
        #pragma unroll
        for (int c = 0; c < 2; c++) {
            int e = c * 256 + tid;
            int r = e >> 2, cq = e & 3;
            float4 a4 = *(const float4*)(Q + (size_t)(m0 + r) * 512 + k0 + cq * 4);
            As[cq*4+0][r] = a4.x; As[cq*4+1][r] = a4.y;
            As[cq*4+2][r] = a4.z; As[cq*4+3][r] = a4.w;
            int kk = e >> 5, nq = e & 31;
            float4 b4 = *(const float4*)(Bsrc + (size_t)(k0 + kk) * 512 + nq * 4);
            *(float4*)&Bs[kk][nq*4] = b4;
        }
        __syncthreads();
        #pragma unroll
        for (int kk = 0; kk < 16; kk++) {
            float a_[8], b_[8];
            *(float4*)&a_[0] = *(float4*)&As[kk][ty*4];
            *(float4*)&a_[4] = *(float4*)&As[kk][64 + ty*4];
            *(float4*)&b_[0] = *(float4*)&Bs[kk][tx*4];
            *(float4*)&b_[4] = *(float4*)&Bs[kk][64 + tx*4];
            #pragma unroll
            for (int i = 0; i < 8; i++)
                #pragma unroll
                for (int j = 0; j < 8; j++)
                    acc[i][j] += a_[i] * b_[j];
        }
        __syncthreads();
    }
    #pragma unroll
    for (int ig = 0; ig < 2; ig++) {
        #pragma unroll
        for (int i = 0; i < 4; i++) {
            int row = m0 + ig*64 + ty*4 + i;
            int b = row >> 11, t = row & 2047;
            #pragma unroll
            for (int jg = 0; jg < 2; jg++) {
                int n = n0 + jg*64 + tx*4;
                float4 r4 = make_float4(acc[ig*4+i][jg*4+0], acc[ig*4+i][jg*4+1],
                                        acc[ig*4+i][jg*4+2], acc[ig*4+i][jg*4+3]);
                if (n < 512) {
                    *(float4*)(qk + ((size_t)((b*8 + (n>>6))*2048 + t))*64 + (n&63)) = r4;
                } else {
                    int nv = n - 512;
                    *(float4*)(vv + ((size_t)((b*8 + (nv>>6))*2048 + t))*64 + (nv&63)) = r4;
                }
            }
        }
    }
}

// ---------------- K1b: reciprocal row norms of qk ----------------
__global__ __launch_bounds__(256) void k_rnorm(const float* __restrict__ qk,
                                               float* __restrict__ rnorm)
{
    int w = threadIdx.x >> 6, lane = threadIdx.x & 63;
    int row = blockIdx.x * 4 + w;            // 0..131071  (bm*2048+t)
    float x = qk[(size_t)row * 64 + lane];
    float s = x * x;
    #pragma unroll
    for (int d = 1; d < 64; d <<= 1) s += __shfl_xor(s, d);
    if (lane == 0) rnorm[row] = 1.0f / fmaxf(sqrtf(s), 1e-12f);
}

// ---------------- K2: hash = f32 GEMM (128 tokens x 4h x 256 cols, K=64) + signed argmax ----------------
__global__ __launch_bounds__(256) void k_hash(const float* __restrict__ qk,
    const float* __restrict__ rotT2, unsigned* __restrict__ buckets)
{
    __shared__ float As[64*128];    // As[k][row], pitch 128 (32 KB)
    __shared__ float Bs[64*132];    // Bs[k][col], pitch 132 (33.8 KB)
    const int bx = blockIdx.x;
    const int bm = bx >> 4;
    const int row0 = (bx & 15) << 7;             // token base within bm
    const int tid = threadIdx.x;
    const int ty = tid >> 4, tx = tid & 15;
    // ---- stage A (128 tokens x 64 k), transposed; conflict-free (rows 0..31/instr) ----
    {
        const int r = tid >> 1;
        const int kb = (tid & 1) * 8;            // float4 units
        const float* src = qk + ((size_t)(bm*2048 + row0 + r))*64;
        #pragma unroll
        for (int c = 0; c < 8; c++) {
            float4 a4 = *(const float4*)(src + (size_t)(kb + c)*4);
            int k = (kb + c)*4;
            As[(k+0)*128 + r] = a4.x;
            As[(k+1)*128 + r] = a4.y;
            As[(k+2)*128 + r] = a4.z;
            As[(k+3)*128 + r] = a4.w;
        }
    }
    for (int h = 0; h < 4; h++) {
        float bv[8]; unsigned bi[8];
        #pragma unroll
        for (int i = 0; i < 8; i++) { bv[i] = -3.402823466e38f; bi[i] = 0u; }
        for (int ch = 0; ch < 2; ch++) {
            __syncthreads();                     // previous readers done
            {   // stage Bs 64 x 128 from rotT2[h][k][ch*128 + col]
                const float* src = rotT2 + (size_t)h*16384 + ch*128;
                #pragma unroll
                for (int c = 0; c < 8; c++) {
                    int e = c*256 + tid;
                    int k = e >> 5, colq = e & 31;
                    float4 b4 = *(const float4*)(src + (size_t)k*256 + colq*4);
                    *(float4*)&Bs[k*132 + colq*4] = b4;
                }
            }
            __syncthreads();
            float acc[8][8] = {};
            #pragma unroll 8
            for (int kk = 0; kk < 64; kk++) {
                float a_[8], b_[8];
                *(float4*)&a_[0] = *(float4*)&As[kk*128 + ty*4];
                *(float4*)&a_[4] = *(float4*)&As[kk*128 + 64 + ty*4];
                *(float4*)&b_[0] = *(float4*)&Bs[kk*132 + tx*4];
                *(float4*)&b_[4] = *(float4*)&Bs[kk*132 + 64 + tx*4];
                #pragma unroll
                for (int i = 0; i < 8; i++)
                    #pragma unroll
                    for (int j = 0; j < 8; j++)
                        acc[i][j] += a_[i] * b_[j];
            }
            // ---- per-thread signed argmax update ----
            #pragma unroll
            for (int j = 0; j < 8; j++) {
                unsigned c0 = (unsigned)(ch*128 + ((j < 4) ? (tx*4 + j) : (64 + tx*4 + (j - 4))));
                unsigned nc0 = 256u + c0;
                #pragma unroll
                for (int i = 0; i < 8; i++) {
                    float v = acc[i][j];
                    if (v > bv[i] || (v == bv[i] && c0 < bi[i])) { bv[i] = v; bi[i] = c0; }
                    float nv = -v;
                    if (nv > bv[i] || (nv == bv[i] && nc0 < bi[i])) { bv[i] = nv; bi[i] = nc0; }
                }
            }
        }
        // ---- reduce over tx (16 lanes) via shuffle butterfly ----
        #pragma unroll
        for (int i = 0; i < 8; i++) {
            #pragma unroll
            for (int d = 1; d < 16; d <<= 1) {
                float ov = __shfl_xor(bv[i], d);
                unsigned oi = (unsigned)__shfl_xor((int)bi[i], d);
                if (ov > bv[i] || (ov == bv[i] && oi < bi[i])) { bv[i] = ov; bi[i] = oi; }
            }
        }
        if (tx == 0) {
            #pragma unroll
            for (int i = 0; i < 8; i++) {
                int r = (i < 4) ? (ty*4 + i) : (64 + ty*4 + (i - 4));
                buckets[((size_t)(bm*4 + h))*2048 + row0 + r] = bi[i];
            }
        }
    }
}

// ---------------- K3: stable counting sort per (bm,hash) ----------------
__global__ __launch_bounds__(256) void k_sort(const unsigned* __restrict__ buckets,
                                              unsigned* __restrict__ st)
{
    __shared__ unsigned whist[4][512];
    __shared__ unsigned baseb[512];
    const int seg = blockIdx.x;                  // bm*4+h
    const unsigned* bk = buckets + (size_t)seg * 2048;
    unsigned* out = st + (size_t)seg * 2048;
    const int tid = threadIdx.x, w = tid >> 6, lane = tid & 63;
    for (int b = tid; b < 2048; b += 256) ((unsigned*)whist)[b] = 0u;
    __syncthreads();
    unsigned myb[8];
    #pragma unroll
    for (int r = 0; r < 8; r++) {
        int pos = w*512 + r*64 + lane;
        myb[r] = bk[pos];
        atomicAdd(&whist[w][myb[r]], 1u);
    }
    __syncthreads();
    for (int b = tid; b < 512; b += 256) {
        unsigned p = 0;
        #pragma unroll
        for (int ww = 0; ww < 4; ww++) { unsigned t = whist[ww][b]; whist[ww][b] = p; p += t; }
        baseb[b] = p;
    }
    __syncthreads();
    if (tid == 0) {
        unsigned run = 0;
        for (int b = 0; b < 512; b++) { unsigned t = baseb[b]; baseb[b] = run; run += t; }
    }
    __syncthreads();
    for (int b = tid; b < 512; b += 256) {
        unsigned bb = baseb[b];
        #pragma unroll
        for (int ww = 0; ww < 4; ww++) whist[ww][b] += bb;
    }
    __syncthreads();
    for (int r = 0; r < 8; r++) {
        unsigned b = myb[r];
        int pos = w*512 + r*64 + lane;
        unsigned base = whist[w][b];             // read before this round's bumps
        unsigned rank = 0;
        for (int j = 0; j < 64; j++) {
            unsigned bj = __shfl(b, j);
            rank += (j < lane && bj == b) ? 1u : 0u;
        }
        out[base + rank] = (unsigned)pos;
        atomicAdd(&whist[w][b], 1u);
    }
}

// ---------------- K4: chunked LSH attention ----------------
__global__ __launch_bounds__(256) void k_attn(const float* __restrict__ qk,
    const float* __restrict__ vv, const float* __restrict__ rnorm,
    const unsigned* __restrict__ st, float* __restrict__ oh,
    float* __restrict__ logits)
{
    __shared__ float qs[68][68];
    __shared__ float vs[68][68];
    __shared__ unsigned P[68];
    __shared__ float rn[68];
    const int sid = blockIdx.x;
    const int stripi = sid & 31;
    const int seg = sid >> 5;
    const int bm = seg >> 2, h = seg & 3;
    const int G0 = (h*512 + stripi*16) * 4;      // first q slot (global, 0..8191)
    const int tid = threadIdx.x;
    for (int j = tid; j < 68; j += 256) {
        int G = (G0 - 4 + j) & 8191;
        int hg = G >> 11, sg = G & 2047;
        unsigned tok = st[((size_t)(bm*4 + hg))*2048 + sg];
        P[j] = tok;
        rn[j] = rnorm[bm*2048 + (int)tok];
    }
    __syncthreads();
    for (int e = tid; e < 68*16; e += 256) {
        int j = e >> 4, fq = e & 15;
        unsigned tok = P[j];
        size_t base = ((size_t)(bm*2048 + (int)tok))*64 + fq*4;
        *(float4*)&qs[j][fq*4] = *(const float4*)(qk + base);
        *(float4*)&vs[j][fq*4] = *(const float4*)(vv + base);
    }
    __syncthreads();
    const int w = tid >> 6, lane = tid & 63;
    const int half = lane >> 5, qi = (lane >> 3) & 3, jj = lane & 7;
    const int fb = lane & 7;
    for (int cp = 0; cp < 2; cp++) {
        int c = w*4 + cp*2 + half;               // local chunk 0..15
        int jq = 4 + c*4 + qi;
        int jk = c*4 + jj;
        float dot = 0.f;
        #pragma unroll
        for (int fq = 0; fq < 16; fq++) {
            float4 q4 = *(float4*)&qs[jq][fq*4];
            float4 k4 = *(float4*)&qs[jk][fq*4];
            dot += q4.x*k4.x + q4.y*k4.y + q4.z*k4.z + q4.w*k4.w;
        }
        dot *= 0.125f * rn[jk];
        if (P[jq] == P[jk]) dot = SELF_VAL;
        float m = dot;
        m = fmaxf(m, __shfl_xor(m, 1));
        m = fmaxf(m, __shfl_xor(m, 2));
        m = fmaxf(m, __shfl_xor(m, 4));
        float ex = expf(dot - m);
        float s = ex;
        s += __shfl_xor(s, 1); s += __shfl_xor(s, 2); s += __shfl_xor(s, 4);
        float lse = m + logf(s);
        float p = expf(dot - lse);
        unsigned tq = P[jq];
        if (jj == 0) logits[((size_t)(bm*4 + h))*2048 + tq] = lse;
        float a0=0,a1=0,a2=0,a3=0,a4a=0,a5=0,a6=0,a7=0;
        #pragma unroll
        for (int j2 = 0; j2 < 8; j2++) {
            float pj = __shfl(p, (lane & 0x38) | j2);
            float4 va = *(float4*)&vs[c*4 + j2][fb*8];
            float4 vb = *(float4*)&vs[c*4 + j2][fb*8 + 4];
            a0 += pj*va.x; a1 += pj*va.y; a2 += pj*va.z; a3 += pj*va.w;
            a4a += pj*vb.x; a5 += pj*vb.y; a6 += pj*vb.z; a7 += pj*vb.w;
        }
        float* dst = oh + ((size_t)((bm*4 + h)*2048 + (int)tq))*64 + fb*8;
        *(float4*)dst = make_float4(a0, a1, a2, a3);
        *(float4*)(dst + 4) = make_float4(a4a, a5, a6, a7);
    }
}

// ---------------- K5: combine hash rounds ----------------
__global__ __launch_bounds__(256) void k_combine(const float* __restrict__ oh,
    const float* __restrict__ logits, float* __restrict__ comb)
{
    int w = threadIdx.x >> 6, lane = threadIdx.x & 63;
    int row = blockIdx.x * 4 + w;                // bm*2048+t
    int bm = row >> 11, t = row & 2047;
    int b = bm >> 3, head = bm & 7;
    float l0 = logits[((size_t)(bm*4 + 0))*2048 + t];
    float l1 = logits[((size_t)(bm*4 + 1))*2048 + t];
    float l2 = logits[((size_t)(bm*4 + 2))*2048 + t];
    float l3 = logits[((size_t)(bm*4 + 3))*2048 + t];
    float m = fmaxf(fmaxf(l0, l1), fmaxf(l2, l3));
    float e0 = expf(l0 - m), e1 = expf(l1 - m), e2 = expf(l2 - m), e3 = expf(l3 - m);
    float inv = 1.0f / (e0 + e1 + e2 + e3);
    float o = 0.f;
    o += (e0*inv) * oh[((size_t)((bm*4+0)*2048 + t))*64 + lane];
    o += (e1*inv) * oh[((size_t)((bm*4+1)*2048 + t))*64 + lane];
    o += (e2*inv) * oh[((size_t)((bm*4+2)*2048 + t))*64 + lane];
    o += (e3*inv) * oh[((size_t)((bm*4+3)*2048 + t))*64 + lane];
    comb[((size_t)(b*2048 + t))*512 + head*64 + lane] = o;
}

// ---------------- K6: output GEMM + bias (f32, 128x128 tile, 8x8/thread) ----------------
__global__ __launch_bounds__(256) void k_gemm_out(
    const float* __restrict__ A, const float* __restrict__ Wout,
    const float* __restrict__ bias, float* __restrict__ out)
{
    __shared__ float As[16][132];
    __shared__ float Bs[16][132];
    const int bx = blockIdx.x;
    const int mt = bx >> 2, nt = bx & 3;
    const int m0 = mt * 128, n0 = nt * 128;
    const int tid = threadIdx.x;
    const int ty = tid >> 4, tx = tid & 15;
    float acc[8][8] = {};
    for (int k0 = 0; k0 < 512; k0 += 16) {
        #pragma unroll
        for (int c = 0; c < 2; c++) {
            int e = c * 256 + tid;
            int r = e >> 2, cq = e & 3;
            float4 a4 = *(const float4*)(A + (size_t)(m0 + r) * 512 + k0 + cq * 4);
            As[cq*4+0][r] = a4.x; As[cq*4+1][r] = a4.y;
            As[cq*4+2][r] = a4.z; As[cq*4+3][r] = a4.w;
            int kk = e >> 5, nq = e & 31;
            float4 b4 = *(const float4*)(Wout + (size_t)(k0 + kk) * 512 + n0 + nq * 4);
            *(float4*)&Bs[kk][nq*4] = b4;
        }
        __syncthreads();
        #pragma unroll
        for (int kk = 0; kk < 16; kk++) {
            float a_[8], b_[8];
            *(float4*)&a_[0] = *(float4*)&As[kk][ty*4];
            *(float4*)&a_[4] = *(float4*)&As[kk][64 + ty*4];
            *(float4*)&b_[0] = *(float4*)&Bs[kk][tx*4];
            *(float4*)&b_[4] = *(float4*)&Bs[kk][64 + tx*4];
            #pragma unroll
            for (int i = 0; i < 8; i++)
                #pragma unroll
                for (int j = 0; j < 8; j++)
                    acc[i][j] += a_[i] * b_[j];
        }
        __syncthreads();
    }
    #pragma unroll
    for (int ig = 0; ig < 2; ig++) {
        #pragma unroll
        for (int i = 0; i < 4; i++) {
            int row = m0 + ig*64 + ty*4 + i;
            #pragma unroll
            for (int jg = 0; jg < 2; jg++) {
                int n = n0 + jg*64 + tx*4;
                float4 bb = *(const float4*)(bias + n);
                float4 r4 = make_float4(acc[ig*4+i][jg*4+0] + bb.x, acc[ig*4+i][jg*4+1] + bb.y,
                                        acc[ig*4+i][jg*4+2] + bb.z, acc[ig*4+i][jg*4+3] + bb.w);
                *(float4*)(out + (size_t)row * 512 + n) = r4;
            }
        }
    }
}

extern "C" void kernel_launch(void* const* d_in, const int* in_sizes, int n_in,
                              void* d_out, int out_size, void* d_ws, size_t ws_size,
                              hipStream_t stream)
{
    const float* Q    = (const float*)d_in[0];
    const float* Wqk  = (const float*)d_in[3];
    const float* Wv   = (const float*)d_in[4];
    const float* Wout = (const float*)d_in[5];
    const float* bout = (const float*)d_in[6];
    const float* rot  = (const float*)d_in[7];
    float* ws = (float*)d_ws;
    float* qk     = ws;                       // 8,388,608
    float* vv     = ws + 8388608;             // 8,388,608
    float* oh     = ws + 16777216;            // 33,554,432
    float* comb   = ws + 50331648;            // 8,388,608
    float* rnorm  = ws + 58720256;            // 131,072
    float* logits = ws + 58851328;            // 524,288
    unsigned* buckets = (unsigned*)(ws + 59375616);   // 524,288
    unsigned* st      = (unsigned*)(ws + 59899904);   // 524,288
    float* rotT2  = ws + 60424192;            // 65,536
    float* out = (float*)d_out;

    k_rotT    <<<dim3(256),  dim3(256), 0, stream>>>(rot, rotT2);
    k_gemm_qkv<<<dim3(1024), dim3(256), 0, stream>>>(Q, Wqk, Wv, qk, vv);
    k_rnorm   <<<dim3(32768),dim3(256), 0, stream>>>(qk, rnorm);
    k_hash    <<<dim3(1024), dim3(256), 0, stream>>>(qk, rotT2, buckets);
    k_sort    <<<dim3(256),  dim3(256), 0, stream>>>(buckets, st);
    k_attn    <<<dim3(8192), dim3(256), 0, stream>>>(qk, vv, rnorm, st, oh, logits);
    k_combine <<<dim3(32768),dim3(256), 0, stream>>>(oh, logits, comb);
    k_gemm_out<<<dim3(512),  dim3(256), 0, stream>>>(comb, Wout, bout, out);
}

// Round 5
// 758.714 us; speedup vs baseline: 1.7085x; 1.1340x over previous
//
#include <hip/hip_runtime.h>
#include <math.h>

#define SELF_VAL (-5e4f)

// ---------------- K0: re-layout rotations -> rotT2[h][k][col]  (4 x 64 x 256) ----------------
__global__ __launch_bounds__(256) void k_rotT(const float* __restrict__ rot,
                                              float* __restrict__ rotT2)
{
    int idx = blockIdx.x * 256 + threadIdx.x;    // 0..65535
    int h = idx >> 14, k = (idx >> 8) & 63, col = idx & 255;
    rotT2[idx] = rot[k * 1024 + h * 256 + col];
}

// ---------------- K1: fused qk/v GEMM (f32, 128x128 tile, 8x8/thread) ----------------
// A = queries (16384 x 512), B = [Wqk | Wv] (512 x 1024)
// writes qk, v head-major: [(b*8+h)][t][dd]
__global__ __launch_bounds__(256) void k_gemm_qkv(
    const float* __restrict__ Q, const float* __restrict__ Wqk,
    const float* __restrict__ Wv, float* __restrict__ qk, float* __restrict__ vv)
{
    __shared__ float As[16][132];   // transposed: As[k][m]
    __shared__ float Bs[16][132];
    const int bx = blockIdx.x;
    const int mt = bx >> 3, nt = bx & 7;
    const int m0 = mt * 128, n0 = nt * 128;
    const int tid = threadIdx.x;
    const int ty = tid >> 4, tx = tid & 15;
    const float* Bsrc = (n0 < 512) ? (Wqk + n0) : (Wv + (n0 - 512));
    float acc[8][8] = {};
    for (int k0 = 0; k0 < 512; k0 += 16) {
        #pragma unroll
        for (int c = 0; c < 2; c++) {
            int e = c * 256 + tid;
            int r = e >> 2, cq = e & 3;
            float4 a4 = *(const float4*)(Q + (size_t)(m0 + r) * 512 + k0 + cq * 4);
            As[cq*4+0][r] = a4.x; As[cq*4+1][r] = a4.y;
            As[cq*4+2][r] = a4.z; As[cq*4+3][r] = a4.w;
            int kk = e >> 5, nq = e & 31;
            float4 b4 = *(const float4*)(Bsrc + (size_t)(k0 + kk) * 512 + nq * 4);
            *(float4*)&Bs[kk][nq*4] = b4;
        }
        __syncthreads();
        #pragma unroll
        for (int kk = 0; kk < 16; kk++) {
            float a_[8], b_[8];
            *(float4*)&a_[0] = *(float4*)&As[kk][ty*4];
            *(float4*)&a_[4] = *(float4*)&As[kk][64 + ty*4];
            *(float4*)&b_[0] = *(float4*)&Bs[kk][tx*4];
            *(float4*)&b_[4] = *(float4*)&Bs[kk][64 + tx*4];
            #pragma unroll
            for (int i = 0; i < 8; i++)
                #pragma unroll
                for (int j = 0; j < 8; j++)
                    acc[i][j] += a_[i] * b_[j];
        }
        __syncthreads();
    }
    #pragma unroll
    for (int ig = 0; ig < 2; ig++) {
        #pragma unroll
        for (int i = 0; i < 4; i++) {
            int row = m0 + ig*64 + ty*4 + i;
            int b = row >> 11, t = row & 2047;
            #pragma unroll
            for (int jg = 0; jg < 2; jg++) {
                int n = n0 + jg*64 + tx*4;
                float4 r4 = make_float4(acc[ig*4+i][jg*4+0], acc[ig*4+i][jg*4+1],
                                        acc[ig*4+i][jg*4+2], acc[ig*4+i][jg*4+3]);
                if (n < 512) {
                    *(float4*)(qk + ((size_t)((b*8 + (n>>6))*2048 + t))*64 + (n&63)) = r4;
                } else {
                    int nv = n - 512;
                    *(float4*)(vv + ((size_t)((b*8 + (nv>>6))*2048 + t))*64 + (nv&63)) = r4;
                }
            }
        }
    }
}

// ---------------- K1b: reciprocal row norms of qk ----------------
__global__ __launch_bounds__(256) void k_rnorm(const float* __restrict__ qk,
                                               float* __restrict__ rnorm)
{
    int w = threadIdx.x >> 6, lane = threadIdx.x & 63;
    int row = blockIdx.x * 4 + w;            // 0..131071  (bm*2048+t)
    float x = qk[(size_t)row * 64 + lane];
    float s = x * x;
    #pragma unroll
    for (int d = 1; d < 64; d <<= 1) s += __shfl_xor(s, d);
    if (lane == 0) rnorm[row] = 1.0f / fmaxf(sqrtf(s), 1e-12f);
}

// ---------------- K2: hash = f32 GEMM (128 tokens x 4h x 256 cols, K=64) + signed argmax ----------------
// LDS: As 32KB + Bs 17.4KB = 49.4KB -> 3 blocks/CU
__global__ __launch_bounds__(256) void k_hash(const float* __restrict__ qk,
    const float* __restrict__ rotT2, unsigned* __restrict__ buckets)
{
    __shared__ float As[64*128];    // As[k][row], pitch 128 (32 KB)
    __shared__ float Bs[64*68];     // Bs[k][col], pitch 68  (17.4 KB)
    const int bx = blockIdx.x;
    const int bm = bx >> 4;
    const int row0 = (bx & 15) << 7;             // token base within bm
    const int tid = threadIdx.x;
    const int ty = tid >> 4, tx = tid & 15;
    // ---- stage A (128 tokens x 64 k), transposed ----
    {
        const int r = tid >> 1;
        const int kb = (tid & 1) * 8;            // float4 units
        const float* src = qk + ((size_t)(bm*2048 + row0 + r))*64;
        #pragma unroll
        for (int c = 0; c < 8; c++) {
            float4 a4 = *(const float4*)(src + (size_t)(kb + c)*4);
            int k = (kb + c)*4;
            As[(k+0)*128 + r] = a4.x;
            As[(k+1)*128 + r] = a4.y;
            As[(k+2)*128 + r] = a4.z;
            As[(k+3)*128 + r] = a4.w;
        }
    }
    for (int h = 0; h < 4; h++) {
        float bv[8]; unsigned bi[8];
        #pragma unroll
        for (int i = 0; i < 8; i++) { bv[i] = -3.402823466e38f; bi[i] = 0u; }
        for (int ch = 0; ch < 4; ch++) {
            __syncthreads();                     // previous readers done
            {   // stage Bs 64 x 64 from rotT2[h][k][ch*64 + col]
                const float* src = rotT2 + (size_t)h*16384 + ch*64;
                #pragma unroll
                for (int c = 0; c < 4; c++) {
                    int e = c*256 + tid;
                    int k = e >> 4, colq = e & 15;
                    float4 b4 = *(const float4*)(src + (size_t)k*256 + colq*4);
                    *(float4*)&Bs[k*68 + colq*4] = b4;
                }
            }
            __syncthreads();
            float acc[8][4] = {};
            #pragma unroll 8
            for (int kk = 0; kk < 64; kk++) {
                float a_[8], b_[4];
                *(float4*)&a_[0] = *(float4*)&As[kk*128 + ty*4];
                *(float4*)&a_[4] = *(float4*)&As[kk*128 + 64 + ty*4];
                *(float4*)&b_[0] = *(float4*)&Bs[kk*68 + tx*4];
                #pragma unroll
                for (int i = 0; i < 8; i++)
                    #pragma unroll
                    for (int j = 0; j < 4; j++)
                        acc[i][j] += a_[i] * b_[j];
            }
            // ---- per-thread signed argmax update ----
            #pragma unroll
            for (int j = 0; j < 4; j++) {
                unsigned c0 = (unsigned)(ch*64 + tx*4 + j);
                unsigned nc0 = 256u + c0;
                #pragma unroll
                for (int i = 0; i < 8; i++) {
                    float v = acc[i][j];
                    if (v > bv[i] || (v == bv[i] && c0 < bi[i])) { bv[i] = v; bi[i] = c0; }
                    float nv = -v;
                    if (nv > bv[i] || (nv == bv[i] && nc0 < bi[i])) { bv[i] = nv; bi[i] = nc0; }
                }
            }
        }
        // ---- reduce over tx (16 lanes) via shuffle butterfly ----
        #pragma unroll
        for (int i = 0; i < 8; i++) {
            #pragma unroll
            for (int d = 1; d < 16; d <<= 1) {
                float ov = __shfl_xor(bv[i], d);
                unsigned oi = (unsigned)__shfl_xor((int)bi[i], d);
                if (ov > bv[i] || (ov == bv[i] && oi < bi[i])) { bv[i] = ov; bi[i] = oi; }
            }
        }
        if (tx == 0) {
            #pragma unroll
            for (int i = 0; i < 8; i++) {
                int r = (i < 4) ? (ty*4 + i) : (64 + ty*4 + (i - 4));
                buckets[((size_t)(bm*4 + h))*2048 + row0 + r] = bi[i];
            }
        }
    }
}

// ---------------- K3: stable counting sort per (bm,hash) ----------------
__global__ __launch_bounds__(256) void k_sort(const unsigned* __restrict__ buckets,
                                              unsigned* __restrict__ st)
{
    __shared__ unsigned whist[4][512];
    __shared__ unsigned baseb[512];
    const int seg = blockIdx.x;                  // bm*4+h
    const unsigned* bk = buckets + (size_t)seg * 2048;
    unsigned* out = st + (size_t)seg * 2048;
    const int tid = threadIdx.x, w = tid >> 6, lane = tid & 63;
    for (int b = tid; b < 2048; b += 256) ((unsigned*)whist)[b] = 0u;
    __syncthreads();
    unsigned myb[8];
    #pragma unroll
    for (int r = 0; r < 8; r++) {
        int pos = w*512 + r*64 + lane;
        myb[r] = bk[pos];
        atomicAdd(&whist[w][myb[r]], 1u);
    }
    __syncthreads();
    for (int b = tid; b < 512; b += 256) {
        unsigned p = 0;
        #pragma unroll
        for (int ww = 0; ww < 4; ww++) { unsigned t = whist[ww][b]; whist[ww][b] = p; p += t; }
        baseb[b] = p;
    }
    __syncthreads();
    if (tid == 0) {
        unsigned run = 0;
        for (int b = 0; b < 512; b++) { unsigned t = baseb[b]; baseb[b] = run; run += t; }
    }
    __syncthreads();
    for (int b = tid; b < 512; b += 256) {
        unsigned bb = baseb[b];
        #pragma unroll
        for (int ww = 0; ww < 4; ww++) whist[ww][b] += bb;
    }
    __syncthreads();
    for (int r = 0; r < 8; r++) {
        unsigned b = myb[r];
        int pos = w*512 + r*64 + lane;
        unsigned base = whist[w][b];             // read before this round's bumps
        unsigned rank = 0;
        for (int j = 0; j < 64; j++) {
            unsigned bj = __shfl(b, j);
            rank += (j < lane && bj == b) ? 1u : 0u;
        }
        out[base + rank] = (unsigned)pos;
        atomicAdd(&whist[w][b], 1u);
    }
}

// ---------------- K4: chunked LSH attention ----------------
__global__ __launch_bounds__(256) void k_attn(const float* __restrict__ qk,
    const float* __restrict__ vv, const float* __restrict__ rnorm,
    const unsigned* __restrict__ st, float* __restrict__ oh,
    float* __restrict__ logits)
{
    __shared__ float qs[68][68];
    __shared__ float vs[68][68];
    __shared__ unsigned P[68];
    __shared__ float rn[68];
    const int sid = blockIdx.x;
    const int stripi = sid & 31;
    const int seg = sid >> 5;
    const int bm = seg >> 2, h = seg & 3;
    const int G0 = (h*512 + stripi*16) * 4;      // first q slot (global, 0..8191)
    const int tid = threadIdx.x;
    for (int j = tid; j < 68; j += 256) {
        int G = (G0 - 4 + j) & 8191;
        int hg = G >> 11, sg = G & 2047;
        unsigned tok = st[((size_t)(bm*4 + hg))*2048 + sg];
        P[j] = tok;
        rn[j] = rnorm[bm*2048 + (int)tok];
    }
    __syncthreads();
    for (int e = tid; e < 68*16; e += 256) {
        int j = e >> 4, fq = e & 15;
        unsigned tok = P[j];
        size_t base = ((size_t)(bm*2048 + (int)tok))*64 + fq*4;
        *(float4*)&qs[j][fq*4] = *(const float4*)(qk + base);
        *(float4*)&vs[j][fq*4] = *(const float4*)(vv + base);
    }
    __syncthreads();
    const int w = tid >> 6, lane = tid & 63;
    const int half = lane >> 5, qi = (lane >> 3) & 3, jj = lane & 7;
    const int fb = lane & 7;
    for (int cp = 0; cp < 2; cp++) {
        int c = w*4 + cp*2 + half;               // local chunk 0..15
        int jq = 4 + c*4 + qi;
        int jk = c*4 + jj;
        float dot = 0.f;
        #pragma unroll
        for (int fq = 0; fq < 16; fq++) {
            float4 q4 = *(float4*)&qs[jq][fq*4];
            float4 k4 = *(float4*)&qs[jk][fq*4];
            dot += q4.x*k4.x + q4.y*k4.y + q4.z*k4.z + q4.w*k4.w;
        }
        dot *= 0.125f * rn[jk];
        if (P[jq] == P[jk]) dot = SELF_VAL;
        float m = dot;
        m = fmaxf(m, __shfl_xor(m, 1));
        m = fmaxf(m, __shfl_xor(m, 2));
        m = fmaxf(m, __shfl_xor(m, 4));
        float ex = expf(dot - m);
        float s = ex;
        s += __shfl_xor(s, 1); s += __shfl_xor(s, 2); s += __shfl_xor(s, 4);
        float lse = m + logf(s);
        float p = expf(dot - lse);
        unsigned tq = P[jq];
        if (jj == 0) logits[((size_t)(bm*4 + h))*2048 + tq] = lse;
        float a0=0,a1=0,a2=0,a3=0,a4a=0,a5=0,a6=0,a7=0;
        #pragma unroll
        for (int j2 = 0; j2 < 8; j2++) {
            float pj = __shfl(p, (lane & 0x38) | j2);
            float4 va = *(float4*)&vs[c*4 + j2][fb*8];
            float4 vb = *(float4*)&vs[c*4 + j2][fb*8 + 4];
            a0 += pj*va.x; a1 += pj*va.y; a2 += pj*va.z; a3 += pj*va.w;
            a4a += pj*vb.x; a5 += pj*vb.y; a6 += pj*vb.z; a7 += pj*vb.w;
        }
        float* dst = oh + ((size_t)((bm*4 + h)*2048 + (int)tq))*64 + fb*8;
        *(float4*)dst = make_float4(a0, a1, a2, a3);
        *(float4*)(dst + 4) = make_float4(a4a, a5, a6, a7);
    }
}

// ---------------- K5: combine hash rounds ----------------
__global__ __launch_bounds__(256) void k_combine(const float* __restrict__ oh,
    const float* __restrict__ logits, float* __restrict__ comb)
{
    int w = threadIdx.x >> 6, lane = threadIdx.x & 63;
    int row = blockIdx.x * 4 + w;                // bm*2048+t
    int bm = row >> 11, t = row & 2047;
    int b = bm >> 3, head = bm & 7;
    float l0 = logits[((size_t)(bm*4 + 0))*2048 + t];
    float l1 = logits[((size_t)(bm*4 + 1))*2048 + t];
    float l2 = logits[((size_t)(bm*4 + 2))*2048 + t];
    float l3 = logits[((size_t)(bm*4 + 3))*2048 + t];
    float m = fmaxf(fmaxf(l0, l1), fmaxf(l2, l3));
    float e0 = expf(l0 - m), e1 = expf(l1 - m), e2 = expf(l2 - m), e3 = expf(l3 - m);
    float inv = 1.0f / (e0 + e1 + e2 + e3);
    float o = 0.f;
    o += (e0*inv) * oh[((size_t)((bm*4+0)*2048 + t))*64 + lane];
    o += (e1*inv) * oh[((size_t)((bm*4+1)*2048 + t))*64 + lane];
    o += (e2*inv) * oh[((size_t)((bm*4+2)*2048 + t))*64 + lane];
    o += (e3*inv) * oh[((size_t)((bm*4+3)*2048 + t))*64 + lane];
    comb[((size_t)(b*2048 + t))*512 + head*64 + lane] = o;
}

// ---------------- K6: output GEMM + bias (f32, 128x128 tile, 8x8/thread) ----------------
__global__ __launch_bounds__(256) void k_gemm_out(
    const float* __restrict__ A, const float* __restrict__ Wout,
    const float* __restrict__ bias, float* __restrict__ out)
{
    __shared__ float As[16][132];
    __shared__ float Bs[16][132];
    const int bx = blockIdx.x;
    const int mt = bx >> 2, nt = bx & 3;
    const int m0 = mt * 128, n0 = nt * 128;
    const int tid = threadIdx.x;
    const int ty = tid >> 4, tx = tid & 15;
    float acc[8][8] = {};
    for (int k0 = 0; k0 < 512; k0 += 16) {
        #pragma unroll
        for (int c = 0; c < 2; c++) {
            int e = c * 256 + tid;
            int r = e >> 2, cq = e & 3;
            float4 a4 = *(const float4*)(A + (size_t)(m0 + r) * 512 + k0 + cq * 4);
            As[cq*4+0][r] = a4.x; As[cq*4+1][r] = a4.y;
            As[cq*4+2][r] = a4.z; As[cq*4+3][r] = a4.w;
            int kk = e >> 5, nq = e & 31;
            float4 b4 = *(const float4*)(Wout + (size_t)(k0 + kk) * 512 + n0 + nq * 4);
            *(float4*)&Bs[kk][nq*4] = b4;
        }
        __syncthreads();
        #pragma unroll
        for (int kk = 0; kk < 16; kk++) {
            float a_[8], b_[8];
            *(float4*)&a_[0] = *(float4*)&As[kk][ty*4];
            *(float4*)&a_[4] = *(float4*)&As[kk][64 + ty*4];
            *(float4*)&b_[0] = *(float4*)&Bs[kk][tx*4];
            *(float4*)&b_[4] = *(float4*)&Bs[kk][64 + tx*4];
            #pragma unroll
            for (int i = 0; i < 8; i++)
                #pragma unroll
                for (int j = 0; j < 8; j++)
                    acc[i][j] += a_[i] * b_[j];
        }
        __syncthreads();
    }
    #pragma unroll
    for (int ig = 0; ig < 2; ig++) {
        #pragma unroll
        for (int i = 0; i < 4; i++) {
            int row = m0 + ig*64 + ty*4 + i;
            #pragma unroll
            for (int jg = 0; jg < 2; jg++) {
                int n = n0 + jg*64 + tx*4;
                float4 bb = *(const float4*)(bias + n);
                float4 r4 = make_float4(acc[ig*4+i][jg*4+0] + bb.x, acc[ig*4+i][jg*4+1] + bb.y,
                                        acc[ig*4+i][jg*4+2] + bb.z, acc[ig*4+i][jg*4+3] + bb.w);
                *(float4*)(out + (size_t)row * 512 + n) = r4;
            }
        }
    }
}

extern "C" void kernel_launch(void* const* d_in, const int* in_sizes, int n_in,
                              void* d_out, int out_size, void* d_ws, size_t ws_size,
                              hipStream_t stream)
{
    const float* Q    = (const float*)d_in[0];
    const float* Wqk  = (const float*)d_in[3];
    const float* Wv   = (const float*)d_in[4];
    const float* Wout = (const float*)d_in[5];
    const float* bout = (const float*)d_in[6];
    const float* rot  = (const float*)d_in[7];
    float* ws = (float*)d_ws;
    float* qk     = ws;                       // 8,388,608
    float* vv     = ws + 8388608;             // 8,388,608
    float* oh     = ws + 16777216;            // 33,554,432
    float* comb   = ws + 50331648;            // 8,388,608
    float* rnorm  = ws + 58720256;            // 131,072
    float* logits = ws + 58851328;            // 524,288
    unsigned* buckets = (unsigned*)(ws + 59375616);   // 524,288
    unsigned* st      = (unsigned*)(ws + 59899904);   // 524,288
    float* rotT2  = ws + 60424192;            // 65,536
    float* out = (float*)d_out;

    k_rotT    <<<dim3(256),  dim3(256), 0, stream>>>(rot, rotT2);
    k_gemm_qkv<<<dim3(1024), dim3(256), 0, stream>>>(Q, Wqk, Wv, qk, vv);
    k_rnorm   <<<dim3(32768),dim3(256), 0, stream>>>(qk, rnorm);
    k_hash    <<<dim3(1024), dim3(256), 0, stream>>>(qk, rotT2, buckets);
    k_sort    <<<dim3(256),  dim3(256), 0, stream>>>(buckets, st);
    k_attn    <<<dim3(8192), dim3(256), 0, stream>>>(qk, vv, rnorm, st, oh, logits);
    k_combine <<<dim3(32768),dim3(256), 0, stream>>>(oh, logits, comb);
    k_gemm_out<<<dim3(512),  dim3(256), 0, stream>>>(comb, Wout, bout, out);
}

// Round 6
// 748.321 us; speedup vs baseline: 1.7322x; 1.0139x over previous
//
#include <hip/hip_runtime.h>
#include <math.h>

#define SELF_VAL (-5e4f)

// ---------------- K0: re-layout rotations -> rotT2[h][k][col]  (4 x 64 x 256) ----------------
__global__ __launch_bounds__(256) void k_rotT(const float* __restrict__ rot,
                                              float* __restrict__ rotT2)
{
    int idx = blockIdx.x * 256 + threadIdx.x;    // 0..65535
    int h = idx >> 14, k = (idx >> 8) & 63, col = idx & 255;
    rotT2[idx] = rot[k * 1024 + h * 256 + col];
}

// ---------------- K1: fused qk/v GEMM (f32, 128x128 tile, 8x8/thread) ----------------
// A = queries (16384 x 512), B = [Wqk | Wv] (512 x 1024)
// writes qk, v head-major: [(b*8+h)][t][dd]
__global__ __launch_bounds__(256) void k_gemm_qkv(
    const float* __restrict__ Q, const float* __restrict__ Wqk,
    const float* __restrict__ Wv, float* __restrict__ qk, float* __restrict__ vv)
{
    __shared__ float As[16][132];   // transposed: As[k][m]
    __shared__ float Bs[16][132];
    const int bx = blockIdx.x;
    const int mt = bx >> 3, nt = bx & 7;
    const int m0 = mt * 128, n0 = nt * 128;
    const int tid = threadIdx.x;
    const int ty = tid >> 4, tx = tid & 15;
    const float* Bsrc = (n0 < 512) ? (Wqk + n0) : (Wv + (n0 - 512));
    float acc[8][8] = {};
    for (int k0 = 0; k0 < 512; k0 += 16) {
        #pragma unroll
        for (int c = 0; c < 2; c++) {
            int e = c * 256 + tid;
            int r = e >> 2, cq = e & 3;
            float4 a4 = *(const float4*)(Q + (size_t)(m0 + r) * 512 + k0 + cq * 4);
            As[cq*4+0][r] = a4.x; As[cq*4+1][r] = a4.y;
            As[cq*4+2][r] = a4.z; As[cq*4+3][r] = a4.w;
            int kk = e >> 5, nq = e & 31;
            float4 b4 = *(const float4*)(Bsrc + (size_t)(k0 + kk) * 512 + nq * 4);
            *(float4*)&Bs[kk][nq*4] = b4;
        }
        __syncthreads();
        #pragma unroll
        for (int kk = 0; kk < 16; kk++) {
            float a_[8], b_[8];
            *(float4*)&a_[0] = *(float4*)&As[kk][ty*4];
            *(float4*)&a_[4] = *(float4*)&As[kk][64 + ty*4];
            *(float4*)&b_[0] = *(float4*)&Bs[kk][tx*4];
            *(float4*)&b_[4] = *(float4*)&Bs[kk][64 + tx*4];
            #pragma unroll
            for (int i = 0; i < 8; i++)
                #pragma unroll
                for (int j = 0; j < 8; j++)
                    acc[i][j] += a_[i] * b_[j];
        }
        __syncthreads();
    }
    #pragma unroll
    for (int ig = 0; ig < 2; ig++) {
        #pragma unroll
        for (int i = 0; i < 4; i++) {
            int row = m0 + ig*64 + ty*4 + i;
            int b = row >> 11, t = row & 2047;
            #pragma unroll
            for (int jg = 0; jg < 2; jg++) {
                int n = n0 + jg*64 + tx*4;
                float4 r4 = make_float4(acc[ig*4+i][jg*4+0], acc[ig*4+i][jg*4+1],
                                        acc[ig*4+i][jg*4+2], acc[ig*4+i][jg*4+3]);
                if (n < 512) {
                    *(float4*)(qk + ((size_t)((b*8 + (n>>6))*2048 + t))*64 + (n&63)) = r4;
                } else {
                    int nv = n - 512;
                    *(float4*)(vv + ((size_t)((b*8 + (nv>>6))*2048 + t))*64 + (nv&63)) = r4;
                }
            }
        }
    }
}

// ---------------- K1b: reciprocal row norms of qk ----------------
__global__ __launch_bounds__(256) void k_rnorm(const float* __restrict__ qk,
                                               float* __restrict__ rnorm)
{
    int w = threadIdx.x >> 6, lane = threadIdx.x & 63;
    int row = blockIdx.x * 4 + w;            // 0..131071  (bm*2048+t)
    float x = qk[(size_t)row * 64 + lane];
    float s = x * x;
    #pragma unroll
    for (int d = 1; d < 64; d <<= 1) s += __shfl_xor(s, d);
    if (lane == 0) rnorm[row] = 1.0f / fmaxf(sqrtf(s), 1e-12f);
}

// ---------------- K2: hash = f32 GEMM (128 tokens, K=64) + signed argmax ----------------
// A in LDS (32 KB only); B streamed from global (L2-resident, 256 KB total).
// ONE barrier in the whole kernel; no B staging, no per-chunk syncs.
__global__ __launch_bounds__(256) void k_hash(const float* __restrict__ qk,
    const float* __restrict__ rotT2, unsigned* __restrict__ buckets)
{
    __shared__ float As[64*128];    // As[k][row], pitch 128 (32 KB)
    const int bx = blockIdx.x;
    const int bm = bx >> 4;
    const int row0 = (bx & 15) << 7;             // token base within bm
    const int tid = threadIdx.x;
    const int ty = tid >> 4, tx = tid & 15;
    // ---- stage A (128 tokens x 64 k), transposed ----
    {
        const int r = tid >> 1;
        const int kb = (tid & 1) * 8;            // float4 units
        const float* src = qk + ((size_t)(bm*2048 + row0 + r))*64;
        #pragma unroll
        for (int c = 0; c < 8; c++) {
            float4 a4 = *(const float4*)(src + (size_t)(kb + c)*4);
            int k = (kb + c)*4;
            As[(k+0)*128 + r] = a4.x;
            As[(k+1)*128 + r] = a4.y;
            As[(k+2)*128 + r] = a4.z;
            As[(k+3)*128 + r] = a4.w;
        }
    }
    __syncthreads();
    #pragma unroll 1
    for (int h = 0; h < 4; h++) {
        float bv[8]; unsigned bi[8];
        #pragma unroll
        for (int i = 0; i < 8; i++) { bv[i] = -3.402823466e38f; bi[i] = 0u; }
        #pragma unroll 1
        for (int ch = 0; ch < 4; ch++) {
            const float* bsrc = rotT2 + (size_t)h*16384 + ch*64 + tx*4;
            float acc[8][4] = {};
            #pragma unroll 16
            for (int kk = 0; kk < 64; kk++) {
                float4 b4 = *(const float4*)(bsrc + (size_t)kk*256);
                float a_[8];
                *(float4*)&a_[0] = *(float4*)&As[kk*128 + ty*4];
                *(float4*)&a_[4] = *(float4*)&As[kk*128 + 64 + ty*4];
                float b_[4] = {b4.x, b4.y, b4.z, b4.w};
                #pragma unroll
                for (int i = 0; i < 8; i++)
                    #pragma unroll
                    for (int j = 0; j < 4; j++)
                        acc[i][j] += a_[i] * b_[j];
            }
            // ---- per-thread signed argmax update ----
            #pragma unroll
            for (int j = 0; j < 4; j++) {
                unsigned c0 = (unsigned)(ch*64 + tx*4 + j);
                unsigned nc0 = 256u + c0;
                #pragma unroll
                for (int i = 0; i < 8; i++) {
                    float v = acc[i][j];
                    if (v > bv[i] || (v == bv[i] && c0 < bi[i])) { bv[i] = v; bi[i] = c0; }
                    float nv = -v;
                    if (nv > bv[i] || (nv == bv[i] && nc0 < bi[i])) { bv[i] = nv; bi[i] = nc0; }
                }
            }
        }
        // ---- reduce over tx (16 lanes) via shuffle butterfly ----
        #pragma unroll
        for (int i = 0; i < 8; i++) {
            #pragma unroll
            for (int d = 1; d < 16; d <<= 1) {
                float ov = __shfl_xor(bv[i], d);
                unsigned oi = (unsigned)__shfl_xor((int)bi[i], d);
                if (ov > bv[i] || (ov == bv[i] && oi < bi[i])) { bv[i] = ov; bi[i] = oi; }
            }
        }
        if (tx == 0) {
            #pragma unroll
            for (int i = 0; i < 8; i++) {
                int r = (i < 4) ? (ty*4 + i) : (64 + ty*4 + (i - 4));
                buckets[((size_t)(bm*4 + h))*2048 + row0 + r] = bi[i];
            }
        }
    }
}

// ---------------- K3: stable counting sort per (bm,hash) ----------------
__global__ __launch_bounds__(256) void k_sort(const unsigned* __restrict__ buckets,
                                              unsigned* __restrict__ st)
{
    __shared__ unsigned whist[4][512];
    __shared__ unsigned baseb[512];
    const int seg = blockIdx.x;                  // bm*4+h
    const unsigned* bk = buckets + (size_t)seg * 2048;
    unsigned* out = st + (size_t)seg * 2048;
    const int tid = threadIdx.x, w = tid >> 6, lane = tid & 63;
    for (int b = tid; b < 2048; b += 256) ((unsigned*)whist)[b] = 0u;
    __syncthreads();
    unsigned myb[8];
    #pragma unroll
    for (int r = 0; r < 8; r++) {
        int pos = w*512 + r*64 + lane;
        myb[r] = bk[pos];
        atomicAdd(&whist[w][myb[r]], 1u);
    }
    __syncthreads();
    for (int b = tid; b < 512; b += 256) {
        unsigned p = 0;
        #pragma unroll
        for (int ww = 0; ww < 4; ww++) { unsigned t = whist[ww][b]; whist[ww][b] = p; p += t; }
        baseb[b] = p;
    }
    __syncthreads();
    if (tid == 0) {
        unsigned run = 0;
        for (int b = 0; b < 512; b++) { unsigned t = baseb[b]; baseb[b] = run; run += t; }
    }
    __syncthreads();
    for (int b = tid; b < 512; b += 256) {
        unsigned bb = baseb[b];
        #pragma unroll
        for (int ww = 0; ww < 4; ww++) whist[ww][b] += bb;
    }
    __syncthreads();
    for (int r = 0; r < 8; r++) {
        unsigned b = myb[r];
        int pos = w*512 + r*64 + lane;
        unsigned base = whist[w][b];             // read before this round's bumps
        unsigned rank = 0;
        for (int j = 0; j < 64; j++) {
            unsigned bj = __shfl(b, j);
            rank += (j < lane && bj == b) ? 1u : 0u;
        }
        out[base + rank] = (unsigned)pos;
        atomicAdd(&whist[w][b], 1u);
    }
}

// ---------------- K4: chunked LSH attention ----------------
__global__ __launch_bounds__(256) void k_attn(const float* __restrict__ qk,
    const float* __restrict__ vv, const float* __restrict__ rnorm,
    const unsigned* __restrict__ st, float* __restrict__ oh,
    float* __restrict__ logits)
{
    __shared__ float qs[68][68];
    __shared__ float vs[68][68];
    __shared__ unsigned P[68];
    __shared__ float rn[68];
    const int sid = blockIdx.x;
    const int stripi = sid & 31;
    const int seg = sid >> 5;
    const int bm = seg >> 2, h = seg & 3;
    const int G0 = (h*512 + stripi*16) * 4;      // first q slot (global, 0..8191)
    const int tid = threadIdx.x;
    for (int j = tid; j < 68; j += 256) {
        int G = (G0 - 4 + j) & 8191;
        int hg = G >> 11, sg = G & 2047;
        unsigned tok = st[((size_t)(bm*4 + hg))*2048 + sg];
        P[j] = tok;
        rn[j] = rnorm[bm*2048 + (int)tok];
    }
    __syncthreads();
    for (int e = tid; e < 68*16; e += 256) {
        int j = e >> 4, fq = e & 15;
        unsigned tok = P[j];
        size_t base = ((size_t)(bm*2048 + (int)tok))*64 + fq*4;
        *(float4*)&qs[j][fq*4] = *(const float4*)(qk + base);
        *(float4*)&vs[j][fq*4] = *(const float4*)(vv + base);
    }
    __syncthreads();
    const int w = tid >> 6, lane = tid & 63;
    const int half = lane >> 5, qi = (lane >> 3) & 3, jj = lane & 7;
    const int fb = lane & 7;
    for (int cp = 0; cp < 2; cp++) {
        int c = w*4 + cp*2 + half;               // local chunk 0..15
        int jq = 4 + c*4 + qi;
        int jk = c*4 + jj;
        float dot = 0.f;
        #pragma unroll
        for (int fq = 0; fq < 16; fq++) {
            float4 q4 = *(float4*)&qs[jq][fq*4];
            float4 k4 = *(float4*)&qs[jk][fq*4];
            dot += q4.x*k4.x + q4.y*k4.y + q4.z*k4.z + q4.w*k4.w;
        }
        dot *= 0.125f * rn[jk];
        if (P[jq] == P[jk]) dot = SELF_VAL;
        float m = dot;
        m = fmaxf(m, __shfl_xor(m, 1));
        m = fmaxf(m, __shfl_xor(m, 2));
        m = fmaxf(m, __shfl_xor(m, 4));
        float ex = expf(dot - m);
        float s = ex;
        s += __shfl_xor(s, 1); s += __shfl_xor(s, 2); s += __shfl_xor(s, 4);
        float lse = m + logf(s);
        float p = expf(dot - lse);
        unsigned tq = P[jq];
        if (jj == 0) logits[((size_t)(bm*4 + h))*2048 + tq] = lse;
        float a0=0,a1=0,a2=0,a3=0,a4a=0,a5=0,a6=0,a7=0;
        #pragma unroll
        for (int j2 = 0; j2 < 8; j2++) {
            float pj = __shfl(p, (lane & 0x38) | j2);
            float4 va = *(float4*)&vs[c*4 + j2][fb*8];
            float4 vb = *(float4*)&vs[c*4 + j2][fb*8 + 4];
            a0 += pj*va.x; a1 += pj*va.y; a2 += pj*va.z; a3 += pj*va.w;
            a4a += pj*vb.x; a5 += pj*vb.y; a6 += pj*vb.z; a7 += pj*vb.w;
        }
        float* dst = oh + ((size_t)((bm*4 + h)*2048 + (int)tq))*64 + fb*8;
        *(float4*)dst = make_float4(a0, a1, a2, a3);
        *(float4*)(dst + 4) = make_float4(a4a, a5, a6, a7);
    }
}

// ---------------- K5: combine hash rounds ----------------
__global__ __launch_bounds__(256) void k_combine(const float* __restrict__ oh,
    const float* __restrict__ logits, float* __restrict__ comb)
{
    int w = threadIdx.x >> 6, lane = threadIdx.x & 63;
    int row = blockIdx.x * 4 + w;                // bm*2048+t
    int bm = row >> 11, t = row & 2047;
    int b = bm >> 3, head = bm & 7;
    float l0 = logits[((size_t)(bm*4 + 0))*2048 + t];
    float l1 = logits[((size_t)(bm*4 + 1))*2048 + t];
    float l2 = logits[((size_t)(bm*4 + 2))*2048 + t];
    float l3 = logits[((size_t)(bm*4 + 3))*2048 + t];
    float m = fmaxf(fmaxf(l0, l1), fmaxf(l2, l3));
    float e0 = expf(l0 - m), e1 = expf(l1 - m), e2 = expf(l2 - m), e3 = expf(l3 - m);
    float inv = 1.0f / (e0 + e1 + e2 + e3);
    float o = 0.f;
    o += (e0*inv) * oh[((size_t)((bm*4+0)*2048 + t))*64 + lane];
    o += (e1*inv) * oh[((size_t)((bm*4+1)*2048 + t))*64 + lane];
    o += (e2*inv) * oh[((size_t)((bm*4+2)*2048 + t))*64 + lane];
    o += (e3*inv) * oh[((size_t)((bm*4+3)*2048 + t))*64 + lane];
    comb[((size_t)(b*2048 + t))*512 + head*64 + lane] = o;
}

// ---------------- K6: output GEMM + bias (f32, 128x128 tile, 8x8/thread) ----------------
__global__ __launch_bounds__(256) void k_gemm_out(
    const float* __restrict__ A, const float* __restrict__ Wout,
    const float* __restrict__ bias, float* __restrict__ out)
{
    __shared__ float As[16][132];
    __shared__ float Bs[16][132];
    const int bx = blockIdx.x;
    const int mt = bx >> 2, nt = bx & 3;
    const int m0 = mt * 128, n0 = nt * 128;
    const int tid = threadIdx.x;
    const int ty = tid >> 4, tx = tid & 15;
    float acc[8][8] = {};
    for (int k0 = 0; k0 < 512; k0 += 16) {
        #pragma unroll
        for (int c = 0; c < 2; c++) {
            int e = c * 256 + tid;
            int r = e >> 2, cq = e & 3;
            float4 a4 = *(const float4*)(A + (size_t)(m0 + r) * 512 + k0 + cq * 4);
            As[cq*4+0][r] = a4.x; As[cq*4+1][r] = a4.y;
            As[cq*4+2][r] = a4.z; As[cq*4+3][r] = a4.w;
            int kk = e >> 5, nq = e & 31;
            float4 b4 = *(const float4*)(Wout + (size_t)(k0 + kk) * 512 + n0 + nq * 4);
            *(float4*)&Bs[kk][nq*4] = b4;
        }
        __syncthreads();
        #pragma unroll
        for (int kk = 0; kk < 16; kk++) {
            float a_[8], b_[8];
            *(float4*)&a_[0] = *(float4*)&As[kk][ty*4];
            *(float4*)&a_[4] = *(float4*)&As[kk][64 + ty*4];
            *(float4*)&b_[0] = *(float4*)&Bs[kk][tx*4];
            *(float4*)&b_[4] = *(float4*)&Bs[kk][64 + tx*4];
            #pragma unroll
            for (int i = 0; i < 8; i++)
                #pragma unroll
                for (int j = 0; j < 8; j++)
                    acc[i][j] += a_[i] * b_[j];
        }
        __syncthreads();
    }
    #pragma unroll
    for (int ig = 0; ig < 2; ig++) {
        #pragma unroll
        for (int i = 0; i < 4; i++) {
            int row = m0 + ig*64 + ty*4 + i;
            #pragma unroll
            for (int jg = 0; jg < 2; jg++) {
                int n = n0 + jg*64 + tx*4;
                float4 bb = *(const float4*)(bias + n);
                float4 r4 = make_float4(acc[ig*4+i][jg*4+0] + bb.x, acc[ig*4+i][jg*4+1] + bb.y,
                                        acc[ig*4+i][jg*4+2] + bb.z, acc[ig*4+i][jg*4+3] + bb.w);
                *(float4*)(out + (size_t)row * 512 + n) = r4;
            }
        }
    }
}

extern "C" void kernel_launch(void* const* d_in, const int* in_sizes, int n_in,
                              void* d_out, int out_size, void* d_ws, size_t ws_size,
                              hipStream_t stream)
{
    const float* Q    = (const float*)d_in[0];
    const float* Wqk  = (const float*)d_in[3];
    const float* Wv   = (const float*)d_in[4];
    const float* Wout = (const float*)d_in[5];
    const float* bout = (const float*)d_in[6];
    const float* rot  = (const float*)d_in[7];
    float* ws = (float*)d_ws;
    float* qk     = ws;                       // 8,388,608
    float* vv     = ws + 8388608;             // 8,388,608
    float* oh     = ws + 16777216;            // 33,554,432
    float* comb   = ws + 50331648;            // 8,388,608
    float* rnorm  = ws + 58720256;            // 131,072
    float* logits = ws + 58851328;            // 524,288
    unsigned* buckets = (unsigned*)(ws + 59375616);   // 524,288
    unsigned* st      = (unsigned*)(ws + 59899904);   // 524,288
    float* rotT2  = ws + 60424192;            // 65,536
    float* out = (float*)d_out;

    k_rotT    <<<dim3(256),  dim3(256), 0, stream>>>(rot, rotT2);
    k_gemm_qkv<<<dim3(1024), dim3(256), 0, stream>>>(Q, Wqk, Wv, qk, vv);
    k_rnorm   <<<dim3(32768),dim3(256), 0, stream>>>(qk, rnorm);
    k_hash    <<<dim3(1024), dim3(256), 0, stream>>>(qk, rotT2, buckets);
    k_sort    <<<dim3(256),  dim3(256), 0, stream>>>(buckets, st);
    k_attn    <<<dim3(8192), dim3(256), 0, stream>>>(qk, vv, rnorm, st, oh, logits);
    k_combine <<<dim3(32768),dim3(256), 0, stream>>>(oh, logits, comb);
    k_gemm_out<<<dim3(512),  dim3(256), 0, stream>>>(comb, Wout, bout, out);
}